// Round 1
// baseline (1627.544 us; speedup 1.0000x reference)
//
#include <hip/hip_runtime.h>
#include <math.h>

#define D_MODEL 1024
#define D_STATE 16
#define D_CONV  4
#define D_INNER 2048
#define DT_RANK 64
#define B_SZ    2
#define L_SEQ   2048
#define NROW    (B_SZ * L_SEQ)   // 4096

// ---------------------------------------------------------------------------
// Generic tiled fp32 GEMM:  C[M,N] = A[M,K] @ B[N,K]^T   (M = NROW, M%128==0)
// mode 0: plain      mode 1: softplus(c + bias[col])
// ---------------------------------------------------------------------------
#define BM 128
#define BN 128
#define BK 16

__device__ __forceinline__ float softplus_f(float x) {
    return (x > 20.f) ? x : log1pf(__expf(x));
}

__global__ __launch_bounds__(256) void gemm_tn(
    const float* __restrict__ A, int lda,
    const float* __restrict__ B, int ldb,
    float* __restrict__ C, int ldc,
    int N, int K,
    const float* __restrict__ bias, int mode)
{
    __shared__ float As[BK][BM];
    __shared__ float Bs[BK][BN];
    const int tid  = threadIdx.x;
    const int row0 = blockIdx.y * BM;
    const int col0 = blockIdx.x * BN;
    const int tm = tid >> 4;        // 0..15
    const int tn = tid & 15;        // 0..15
    const int lr = tid >> 1;        // 0..127 (tile row for staging)
    const int lc = (tid & 1) * 8;   // 0 or 8 (k offset for staging)

    float acc[8][8];
#pragma unroll
    for (int i = 0; i < 8; i++)
#pragma unroll
        for (int j = 0; j < 8; j++) acc[i][j] = 0.f;

    for (int k0 = 0; k0 < K; k0 += BK) {
        const float* ap = A + (size_t)(row0 + lr) * lda + k0 + lc;
        float4 a0 = *(const float4*)(ap);
        float4 a1 = *(const float4*)(ap + 4);
        float4 b0 = make_float4(0.f, 0.f, 0.f, 0.f);
        float4 b1 = make_float4(0.f, 0.f, 0.f, 0.f);
        const int brow = col0 + lr;
        if (brow < N) {
            const float* bp = B + (size_t)brow * ldb + k0 + lc;
            b0 = *(const float4*)(bp);
            b1 = *(const float4*)(bp + 4);
        }
        As[lc + 0][lr] = a0.x; As[lc + 1][lr] = a0.y;
        As[lc + 2][lr] = a0.z; As[lc + 3][lr] = a0.w;
        As[lc + 4][lr] = a1.x; As[lc + 5][lr] = a1.y;
        As[lc + 6][lr] = a1.z; As[lc + 7][lr] = a1.w;
        Bs[lc + 0][lr] = b0.x; Bs[lc + 1][lr] = b0.y;
        Bs[lc + 2][lr] = b0.z; Bs[lc + 3][lr] = b0.w;
        Bs[lc + 4][lr] = b1.x; Bs[lc + 5][lr] = b1.y;
        Bs[lc + 6][lr] = b1.z; Bs[lc + 7][lr] = b1.w;
        __syncthreads();

#pragma unroll
        for (int kk = 0; kk < BK; kk++) {
            float ar[8], br[8];
            *(float4*)&ar[0] = *(const float4*)&As[kk][tm * 8];
            *(float4*)&ar[4] = *(const float4*)&As[kk][tm * 8 + 4];
            *(float4*)&br[0] = *(const float4*)&Bs[kk][tn * 8];
            *(float4*)&br[4] = *(const float4*)&Bs[kk][tn * 8 + 4];
#pragma unroll
            for (int i = 0; i < 8; i++)
#pragma unroll
                for (int j = 0; j < 8; j++)
                    acc[i][j] = fmaf(ar[i], br[j], acc[i][j]);
        }
        __syncthreads();
    }

    const int cbase = col0 + tn * 8;
#pragma unroll
    for (int i = 0; i < 8; i++) {
        const int row = row0 + tm * 8 + i;
#pragma unroll
        for (int jj = 0; jj < 2; jj++) {
            const int col = cbase + jj * 4;
            if (col < N) {
                float4 v;
                v.x = acc[i][jj * 4 + 0];
                v.y = acc[i][jj * 4 + 1];
                v.z = acc[i][jj * 4 + 2];
                v.w = acc[i][jj * 4 + 3];
                if (mode == 1) {
                    v.x = softplus_f(v.x + bias[col + 0]);
                    v.y = softplus_f(v.y + bias[col + 1]);
                    v.z = softplus_f(v.z + bias[col + 2]);
                    v.w = softplus_f(v.w + bias[col + 3]);
                }
                *(float4*)(C + (size_t)row * ldc + col) = v;
            }
        }
    }
}

// ---------------------------------------------------------------------------
// Causal depthwise conv1d (K=4, left-pad 3) + bias + SiLU.
// Input: xs half of xz buffer [NROW][2*D_INNER]; output xc [NROW][D_INNER].
// ---------------------------------------------------------------------------
__global__ __launch_bounds__(256) void conv_silu_kernel(
    const float* __restrict__ xz,
    const float* __restrict__ conv_w,   // [D_INNER][1][4]
    const float* __restrict__ conv_b,
    float* __restrict__ xc)
{
    const int idx = blockIdx.x * 256 + threadIdx.x;   // over NROW*D_INNER
    const int d  = idx & (D_INNER - 1);
    const int rt = idx >> 11;                          // row = b*L + t
    const int t  = rt & (L_SEQ - 1);

    const float w0 = conv_w[d * 4 + 0];
    const float w1 = conv_w[d * 4 + 1];
    const float w2 = conv_w[d * 4 + 2];
    const float w3 = conv_w[d * 4 + 3];

    const float* col = xz + d;
    float acc = conv_b[d];
    if (t >= 3) acc = fmaf(w0, col[(size_t)(rt - 3) * (2 * D_INNER)], acc);
    if (t >= 2) acc = fmaf(w1, col[(size_t)(rt - 2) * (2 * D_INNER)], acc);
    if (t >= 1) acc = fmaf(w2, col[(size_t)(rt - 1) * (2 * D_INNER)], acc);
    acc = fmaf(w3, col[(size_t)rt * (2 * D_INNER)], acc);
    const float sig = 1.f / (1.f + __expf(-acc));
    xc[idx] = acc * sig;
}

// ---------------------------------------------------------------------------
// Selective scan, fused with +D*x and *silu(z).
// Thread = (d_local 0..15, n 0..15); block handles one b and 16 d-channels.
// h kept in a single register per thread; shfl_xor(width 16) reduces over n.
// ---------------------------------------------------------------------------
#define T_CH 64

__global__ __launch_bounds__(256) void scan_kernel(
    const float* __restrict__ dtbuf,   // [NROW][D_INNER]
    const float* __restrict__ xc,      // [NROW][D_INNER]
    const float* __restrict__ xz,      // [NROW][2*D_INNER], z at +D_INNER
    const float* __restrict__ xdbl,    // [NROW][96]: [0,64)=dt_r [64,80)=B [80,96)=C
    const float* __restrict__ A_log,   // [D_INNER][16]
    const float* __restrict__ Dvec,    // [D_INNER]
    float* __restrict__ y)             // [NROW][D_INNER]
{
    __shared__ float dt_s[T_CH][16], x_s[T_CH][16], z_s[T_CH][16];
    __shared__ float B_s[T_CH][16], C_s[T_CH][16], y_s[T_CH][16];

    const int tid = threadIdx.x;
    const int dl  = tid >> 4;          // 0..15
    const int n   = tid & 15;          // 0..15
    const int blk = blockIdx.x;        // 0..255
    const int b   = blk >> 7;
    const int d0  = (blk & 127) << 4;
    const int d   = d0 + dl;

    const float A_dn = -expf(A_log[(size_t)d * D_STATE + n]);
    const float D_d  = Dvec[d];
    float h = 0.f;
    const size_t rowbase = (size_t)b * L_SEQ;

    for (int t0 = 0; t0 < L_SEQ; t0 += T_CH) {
#pragma unroll
        for (int i = 0; i < 4; i++) {
            const int idx = i * 256 + tid;        // 0..1023
            const int tt = idx >> 4;
            const int j  = idx & 15;
            const size_t r = rowbase + t0 + tt;
            dt_s[tt][j] = dtbuf[r * D_INNER + d0 + j];
            x_s[tt][j]  = xc[r * D_INNER + d0 + j];
            z_s[tt][j]  = xz[r * (2 * D_INNER) + D_INNER + d0 + j];
            B_s[tt][j]  = xdbl[r * 96 + DT_RANK + j];
            C_s[tt][j]  = xdbl[r * 96 + DT_RANK + D_STATE + j];
        }
        __syncthreads();

        for (int tt = 0; tt < T_CH; tt++) {
            const float dtv = dt_s[tt][dl];
            const float xv  = x_s[tt][dl];
            const float dA  = __expf(dtv * A_dn);
            h = fmaf(dA, h, dtv * xv * B_s[tt][n]);
            float p = h * C_s[tt][n];
            p += __shfl_xor(p, 1, 16);
            p += __shfl_xor(p, 2, 16);
            p += __shfl_xor(p, 4, 16);
            p += __shfl_xor(p, 8, 16);
            if (n == 0) {
                const float zv  = z_s[tt][dl];
                const float sig = 1.f / (1.f + __expf(-zv));
                y_s[tt][dl] = (p + D_d * xv) * (zv * sig);
            }
        }
        __syncthreads();

#pragma unroll
        for (int i = 0; i < 4; i++) {
            const int idx = i * 256 + tid;
            const int tt = idx >> 4;
            const int j  = idx & 15;
            const size_t r = rowbase + t0 + tt;
            y[r * D_INNER + d0 + j] = y_s[tt][j];
        }
        __syncthreads();
    }
}

// ---------------------------------------------------------------------------
extern "C" void kernel_launch(void* const* d_in, const int* in_sizes, int n_in,
                              void* d_out, int out_size, void* d_ws, size_t ws_size,
                              hipStream_t stream) {
    const float* x          = (const float*)d_in[0];
    const float* in_proj_w  = (const float*)d_in[1];
    const float* conv_w     = (const float*)d_in[2];
    const float* conv_b     = (const float*)d_in[3];
    const float* x_proj_w   = (const float*)d_in[4];
    const float* dt_proj_w  = (const float*)d_in[5];
    const float* dt_proj_b  = (const float*)d_in[6];
    const float* A_log      = (const float*)d_in[7];
    const float* Dv         = (const float*)d_in[8];
    const float* out_proj_w = (const float*)d_in[9];
    float* out = (float*)d_out;

    float* ws   = (float*)d_ws;
    float* xz   = ws;                                    // [4096][4096]
    float* xc   = xz   + (size_t)NROW * 2 * D_INNER;     // [4096][2048]
    float* xdbl = xc   + (size_t)NROW * D_INNER;         // [4096][96]
    float* dtb  = xdbl + (size_t)NROW * 96;              // [4096][2048]
    float* yb   = dtb  + (size_t)NROW * D_INNER;         // [4096][2048]

    dim3 blk(256);

    // 1) xz = x @ in_proj_w^T        (M=4096, N=4096, K=1024)
    gemm_tn<<<dim3((2 * D_INNER) / BN, NROW / BM), blk, 0, stream>>>(
        x, D_MODEL, in_proj_w, D_MODEL, xz, 2 * D_INNER,
        2 * D_INNER, D_MODEL, nullptr, 0);

    // 2) causal depthwise conv + bias + SiLU -> xc
    conv_silu_kernel<<<dim3((NROW * D_INNER) / 256), blk, 0, stream>>>(
        xz, conv_w, conv_b, xc);

    // 3) x_dbl = xc @ x_proj_w^T     (M=4096, N=96, K=2048)
    gemm_tn<<<dim3(1, NROW / BM), blk, 0, stream>>>(
        xc, D_INNER, x_proj_w, D_INNER, xdbl, 96,
        96, D_INNER, nullptr, 0);

    // 4) dt = softplus(dt_r @ dt_proj_w^T + b)   (M=4096, N=2048, K=64)
    gemm_tn<<<dim3(D_INNER / BN, NROW / BM), blk, 0, stream>>>(
        xdbl, 96, dt_proj_w, DT_RANK, dtb, D_INNER,
        D_INNER, DT_RANK, dt_proj_b, 1);

    // 5) selective scan fused with +D*x and *silu(z) -> yb
    scan_kernel<<<dim3(B_SZ * D_INNER / 16), blk, 0, stream>>>(
        dtb, xc, xz, xdbl, A_log, Dv, yb);

    // 6) out = yb @ out_proj_w^T     (M=4096, N=1024, K=2048)
    gemm_tn<<<dim3(D_MODEL / BN, NROW / BM), blk, 0, stream>>>(
        yb, D_INNER, out_proj_w, D_INNER, out, D_MODEL,
        D_MODEL, D_INNER, nullptr, 0);
}

// Round 2
// 1294.763 us; speedup vs baseline: 1.2570x; 1.2570x over previous
//
#include <hip/hip_runtime.h>
#include <math.h>

#define D_MODEL 1024
#define D_STATE 16
#define D_CONV  4
#define D_INNER 2048
#define DT_RANK 64
#define B_SZ    2
#define L_SEQ   2048
#define NROW    (B_SZ * L_SEQ)   // 4096

// ---------------------------------------------------------------------------
// Generic tiled fp32 GEMM:  C[M,N] = A[M,K] @ B[N,K]^T   (M = NROW, M%128==0)
// mode 0: plain      mode 1: softplus(c + bias[col])
// ---------------------------------------------------------------------------
#define BM 128
#define BN 128
#define BK 16

__device__ __forceinline__ float softplus_f(float x) {
    return (x > 20.f) ? x : log1pf(__expf(x));
}

__global__ __launch_bounds__(256) void gemm_tn(
    const float* __restrict__ A, int lda,
    const float* __restrict__ B, int ldb,
    float* __restrict__ C, int ldc,
    int N, int K,
    const float* __restrict__ bias, int mode)
{
    __shared__ float As[BK][BM];
    __shared__ float Bs[BK][BN];
    const int tid  = threadIdx.x;
    const int row0 = blockIdx.y * BM;
    const int col0 = blockIdx.x * BN;
    const int tm = tid >> 4;        // 0..15
    const int tn = tid & 15;        // 0..15
    const int lr = tid >> 1;        // 0..127 (tile row for staging)
    const int lc = (tid & 1) * 8;   // 0 or 8 (k offset for staging)

    float acc[8][8];
#pragma unroll
    for (int i = 0; i < 8; i++)
#pragma unroll
        for (int j = 0; j < 8; j++) acc[i][j] = 0.f;

    for (int k0 = 0; k0 < K; k0 += BK) {
        const float* ap = A + (size_t)(row0 + lr) * lda + k0 + lc;
        float4 a0 = *(const float4*)(ap);
        float4 a1 = *(const float4*)(ap + 4);
        float4 b0 = make_float4(0.f, 0.f, 0.f, 0.f);
        float4 b1 = make_float4(0.f, 0.f, 0.f, 0.f);
        const int brow = col0 + lr;
        if (brow < N) {
            const float* bp = B + (size_t)brow * ldb + k0 + lc;
            b0 = *(const float4*)(bp);
            b1 = *(const float4*)(bp + 4);
        }
        As[lc + 0][lr] = a0.x; As[lc + 1][lr] = a0.y;
        As[lc + 2][lr] = a0.z; As[lc + 3][lr] = a0.w;
        As[lc + 4][lr] = a1.x; As[lc + 5][lr] = a1.y;
        As[lc + 6][lr] = a1.z; As[lc + 7][lr] = a1.w;
        Bs[lc + 0][lr] = b0.x; Bs[lc + 1][lr] = b0.y;
        Bs[lc + 2][lr] = b0.z; Bs[lc + 3][lr] = b0.w;
        Bs[lc + 4][lr] = b1.x; Bs[lc + 5][lr] = b1.y;
        Bs[lc + 6][lr] = b1.z; Bs[lc + 7][lr] = b1.w;
        __syncthreads();

#pragma unroll
        for (int kk = 0; kk < BK; kk++) {
            float ar[8], br[8];
            *(float4*)&ar[0] = *(const float4*)&As[kk][tm * 8];
            *(float4*)&ar[4] = *(const float4*)&As[kk][tm * 8 + 4];
            *(float4*)&br[0] = *(const float4*)&Bs[kk][tn * 8];
            *(float4*)&br[4] = *(const float4*)&Bs[kk][tn * 8 + 4];
#pragma unroll
            for (int i = 0; i < 8; i++)
#pragma unroll
                for (int j = 0; j < 8; j++)
                    acc[i][j] = fmaf(ar[i], br[j], acc[i][j]);
        }
        __syncthreads();
    }

    const int cbase = col0 + tn * 8;
#pragma unroll
    for (int i = 0; i < 8; i++) {
        const int row = row0 + tm * 8 + i;
#pragma unroll
        for (int jj = 0; jj < 2; jj++) {
            const int col = cbase + jj * 4;
            if (col < N) {
                float4 v;
                v.x = acc[i][jj * 4 + 0];
                v.y = acc[i][jj * 4 + 1];
                v.z = acc[i][jj * 4 + 2];
                v.w = acc[i][jj * 4 + 3];
                if (mode == 1) {
                    v.x = softplus_f(v.x + bias[col + 0]);
                    v.y = softplus_f(v.y + bias[col + 1]);
                    v.z = softplus_f(v.z + bias[col + 2]);
                    v.w = softplus_f(v.w + bias[col + 3]);
                }
                *(float4*)(C + (size_t)row * ldc + col) = v;
            }
        }
    }
}

// ---------------------------------------------------------------------------
// Causal depthwise conv1d (K=4, left-pad 3) + bias + SiLU.
// ---------------------------------------------------------------------------
__global__ __launch_bounds__(256) void conv_silu_kernel(
    const float* __restrict__ xz,
    const float* __restrict__ conv_w,   // [D_INNER][1][4]
    const float* __restrict__ conv_b,
    float* __restrict__ xc)
{
    const int idx = blockIdx.x * 256 + threadIdx.x;   // over NROW*D_INNER
    const int d  = idx & (D_INNER - 1);
    const int rt = idx >> 11;                          // row = b*L + t
    const int t  = rt & (L_SEQ - 1);

    const float w0 = conv_w[d * 4 + 0];
    const float w1 = conv_w[d * 4 + 1];
    const float w2 = conv_w[d * 4 + 2];
    const float w3 = conv_w[d * 4 + 3];

    const float* col = xz + d;
    float acc = conv_b[d];
    if (t >= 3) acc = fmaf(w0, col[(size_t)(rt - 3) * (2 * D_INNER)], acc);
    if (t >= 2) acc = fmaf(w1, col[(size_t)(rt - 2) * (2 * D_INNER)], acc);
    if (t >= 1) acc = fmaf(w2, col[(size_t)(rt - 1) * (2 * D_INNER)], acc);
    acc = fmaf(w3, col[(size_t)rt * (2 * D_INNER)], acc);
    const float sig = 1.f / (1.f + __expf(-acc));
    xc[idx] = acc * sig;
}

// ---------------------------------------------------------------------------
// Chunked parallel selective scan.
// h_t = dA_t * h_{t-1} + dt_t*x_t*B_t  is linear in h -> blocked scan:
//   pass1: per chunk g (len 256), compute local h_end (h0=0) and aprod = prod dA
//   pass2: tiny sequential combine over G=8 chunks -> H0[g] (state entering g)
//   pass3: re-run chunk from H0[g], emit y fused with +D*x and *silu(z)
// Grid for pass1/3: B * (D_INNER/16) * G = 2048 blocks -> ~6-8 blocks/CU.
// ---------------------------------------------------------------------------
#define T_CH    64
#define G_CHUNK 8
#define T_CHUNK (L_SEQ / G_CHUNK)   // 256

__global__ __launch_bounds__(256) void scan_pass1(
    const float* __restrict__ dtbuf,   // [NROW][D_INNER]
    const float* __restrict__ xc,      // [NROW][D_INNER]
    const float* __restrict__ xdbl,    // [NROW][96]: [64,80)=B
    const float* __restrict__ A_log,   // [D_INNER][16]
    float* __restrict__ aprod,         // [G][B][D_INNER][16]
    float* __restrict__ hend)          // [G][B][D_INNER][16]
{
    __shared__ float dt_s[T_CH][16], x_s[T_CH][16], B_s[T_CH][16];

    const int tid = threadIdx.x;
    const int dl  = tid >> 4;          // 0..15
    const int n   = tid & 15;          // 0..15
    const int blk = blockIdx.x;        // 0..2047
    const int g   = blk & (G_CHUNK - 1);
    const int db  = (blk >> 3) & 127;
    const int b   = blk >> 10;
    const int d0  = db << 4;
    const int d   = d0 + dl;

    const float A_dn = -expf(A_log[(size_t)d * D_STATE + n]);
    float h = 0.f, ap = 1.f;
    const size_t rowbase = (size_t)b * L_SEQ + (size_t)g * T_CHUNK;

    for (int t0 = 0; t0 < T_CHUNK; t0 += T_CH) {
#pragma unroll
        for (int i = 0; i < 4; i++) {
            const int idx = i * 256 + tid;        // 0..1023
            const int tt = idx >> 4;
            const int j  = idx & 15;
            const size_t r = rowbase + t0 + tt;
            dt_s[tt][j] = dtbuf[r * D_INNER + d0 + j];
            x_s[tt][j]  = xc[r * D_INNER + d0 + j];
            B_s[tt][j]  = xdbl[r * 96 + DT_RANK + j];
        }
        __syncthreads();

#pragma unroll 8
        for (int tt = 0; tt < T_CH; tt++) {
            const float dtv = dt_s[tt][dl];
            const float xv  = x_s[tt][dl];
            const float dA  = __expf(dtv * A_dn);
            ap *= dA;
            h = fmaf(dA, h, dtv * xv * B_s[tt][n]);
        }
        __syncthreads();
    }

    const size_t o = (((size_t)g * B_SZ + b) * D_INNER + d) * D_STATE + n;
    aprod[o] = ap;
    hend[o]  = h;
}

__global__ __launch_bounds__(256) void scan_pass2(
    const float* __restrict__ aprod,
    const float* __restrict__ hend,
    float* __restrict__ H0)
{
    const int idx = blockIdx.x * 256 + threadIdx.x;   // over B*D_INNER*16
    const size_t stride = (size_t)B_SZ * D_INNER * D_STATE;
    float h = 0.f;
#pragma unroll
    for (int g = 0; g < G_CHUNK; g++) {
        H0[(size_t)g * stride + idx] = h;
        h = fmaf(aprod[(size_t)g * stride + idx], h, hend[(size_t)g * stride + idx]);
    }
}

__global__ __launch_bounds__(256) void scan_pass3(
    const float* __restrict__ dtbuf,   // [NROW][D_INNER]
    const float* __restrict__ xc,      // [NROW][D_INNER]
    const float* __restrict__ xz,      // [NROW][2*D_INNER], z at +D_INNER
    const float* __restrict__ xdbl,    // [NROW][96]
    const float* __restrict__ A_log,   // [D_INNER][16]
    const float* __restrict__ Dvec,    // [D_INNER]
    const float* __restrict__ H0,      // [G][B][D_INNER][16]
    float* __restrict__ y)             // [NROW][D_INNER]
{
    __shared__ float dt_s[T_CH][16], x_s[T_CH][16], z_s[T_CH][16];
    __shared__ float B_s[T_CH][16], C_s[T_CH][16], y_s[T_CH][16];

    const int tid = threadIdx.x;
    const int dl  = tid >> 4;
    const int n   = tid & 15;
    const int blk = blockIdx.x;
    const int g   = blk & (G_CHUNK - 1);
    const int db  = (blk >> 3) & 127;
    const int b   = blk >> 10;
    const int d0  = db << 4;
    const int d   = d0 + dl;

    const float A_dn = -expf(A_log[(size_t)d * D_STATE + n]);
    const float D_d  = Dvec[d];
    float h = H0[(((size_t)g * B_SZ + b) * D_INNER + d) * D_STATE + n];
    const size_t rowbase = (size_t)b * L_SEQ + (size_t)g * T_CHUNK;

    for (int t0 = 0; t0 < T_CHUNK; t0 += T_CH) {
#pragma unroll
        for (int i = 0; i < 4; i++) {
            const int idx = i * 256 + tid;
            const int tt = idx >> 4;
            const int j  = idx & 15;
            const size_t r = rowbase + t0 + tt;
            dt_s[tt][j] = dtbuf[r * D_INNER + d0 + j];
            x_s[tt][j]  = xc[r * D_INNER + d0 + j];
            z_s[tt][j]  = xz[r * (2 * D_INNER) + D_INNER + d0 + j];
            B_s[tt][j]  = xdbl[r * 96 + DT_RANK + j];
            C_s[tt][j]  = xdbl[r * 96 + DT_RANK + D_STATE + j];
        }
        __syncthreads();

        for (int tt = 0; tt < T_CH; tt++) {
            const float dtv = dt_s[tt][dl];
            const float xv  = x_s[tt][dl];
            const float dA  = __expf(dtv * A_dn);
            h = fmaf(dA, h, dtv * xv * B_s[tt][n]);
            float p = h * C_s[tt][n];
            p += __shfl_xor(p, 1, 16);
            p += __shfl_xor(p, 2, 16);
            p += __shfl_xor(p, 4, 16);
            p += __shfl_xor(p, 8, 16);
            if (n == 0) {
                const float zv  = z_s[tt][dl];
                const float sig = 1.f / (1.f + __expf(-zv));
                y_s[tt][dl] = (p + D_d * xv) * (zv * sig);
            }
        }
        __syncthreads();

#pragma unroll
        for (int i = 0; i < 4; i++) {
            const int idx = i * 256 + tid;
            const int tt = idx >> 4;
            const int j  = idx & 15;
            const size_t r = rowbase + t0 + tt;
            y[r * D_INNER + d0 + j] = y_s[tt][j];
        }
        __syncthreads();
    }
}

// ---------------------------------------------------------------------------
extern "C" void kernel_launch(void* const* d_in, const int* in_sizes, int n_in,
                              void* d_out, int out_size, void* d_ws, size_t ws_size,
                              hipStream_t stream) {
    const float* x          = (const float*)d_in[0];
    const float* in_proj_w  = (const float*)d_in[1];
    const float* conv_w     = (const float*)d_in[2];
    const float* conv_b     = (const float*)d_in[3];
    const float* x_proj_w   = (const float*)d_in[4];
    const float* dt_proj_w  = (const float*)d_in[5];
    const float* dt_proj_b  = (const float*)d_in[6];
    const float* A_log      = (const float*)d_in[7];
    const float* Dv         = (const float*)d_in[8];
    const float* out_proj_w = (const float*)d_in[9];
    float* out = (float*)d_out;

    float* ws   = (float*)d_ws;
    float* xz   = ws;                                    // [4096][4096]
    float* xc   = xz   + (size_t)NROW * 2 * D_INNER;     // [4096][2048]
    float* xdbl = xc   + (size_t)NROW * D_INNER;         // [4096][96]
    float* dtb  = xdbl + (size_t)NROW * 96;              // [4096][2048]
    float* yb   = dtb  + (size_t)NROW * D_INNER;         // [4096][2048]
    float* apr  = yb   + (size_t)NROW * D_INNER;         // [8][2][2048][16]
    float* hen  = apr  + (size_t)G_CHUNK * B_SZ * D_INNER * D_STATE;
    float* H0   = hen  + (size_t)G_CHUNK * B_SZ * D_INNER * D_STATE;

    dim3 blk(256);

    // 1) xz = x @ in_proj_w^T        (M=4096, N=4096, K=1024)
    gemm_tn<<<dim3((2 * D_INNER) / BN, NROW / BM), blk, 0, stream>>>(
        x, D_MODEL, in_proj_w, D_MODEL, xz, 2 * D_INNER,
        2 * D_INNER, D_MODEL, nullptr, 0);

    // 2) causal depthwise conv + bias + SiLU -> xc
    conv_silu_kernel<<<dim3((NROW * D_INNER) / 256), blk, 0, stream>>>(
        xz, conv_w, conv_b, xc);

    // 3) x_dbl = xc @ x_proj_w^T     (M=4096, N=96, K=2048)
    gemm_tn<<<dim3(1, NROW / BM), blk, 0, stream>>>(
        xc, D_INNER, x_proj_w, D_INNER, xdbl, 96,
        96, D_INNER, nullptr, 0);

    // 4) dt = softplus(dt_r @ dt_proj_w^T + b)   (M=4096, N=2048, K=64)
    gemm_tn<<<dim3(D_INNER / BN, NROW / BM), blk, 0, stream>>>(
        xdbl, 96, dt_proj_w, DT_RANK, dtb, D_INNER,
        D_INNER, DT_RANK, dt_proj_b, 1);

    // 5) chunked parallel selective scan -> yb
    scan_pass1<<<dim3(B_SZ * (D_INNER / 16) * G_CHUNK), blk, 0, stream>>>(
        dtb, xc, xdbl, A_log, apr, hen);
    scan_pass2<<<dim3(B_SZ * D_INNER * D_STATE / 256), blk, 0, stream>>>(
        apr, hen, H0);
    scan_pass3<<<dim3(B_SZ * (D_INNER / 16) * G_CHUNK), blk, 0, stream>>>(
        dtb, xc, xz, xdbl, A_log, Dv, H0, yb);

    // 6) out = yb @ out_proj_w^T     (M=4096, N=1024, K=2048)
    gemm_tn<<<dim3(D_MODEL / BN, NROW / BM), blk, 0, stream>>>(
        yb, D_INNER, out_proj_w, D_INNER, out, D_MODEL,
        D_MODEL, D_INNER, nullptr, 0);
}

// Round 3
// 541.817 us; speedup vs baseline: 3.0039x; 2.3897x over previous
//
#include <hip/hip_runtime.h>
#include <math.h>

#define D_MODEL 1024
#define D_STATE 16
#define D_CONV  4
#define D_INNER 2048
#define DT_RANK 64
#define B_SZ    2
#define L_SEQ   2048
#define NROW    (B_SZ * L_SEQ)   // 4096

typedef __bf16 bf16x8 __attribute__((ext_vector_type(8)));
typedef float  f32x4  __attribute__((ext_vector_type(4)));

__device__ __forceinline__ unsigned short f2bf(float f) {
    unsigned u = __float_as_uint(f);
    u += 0x7fff + ((u >> 16) & 1);       // RNE
    return (unsigned short)(u >> 16);
}

__device__ __forceinline__ float softplus_f(float x) {
    return (x > 20.f) ? x : log1pf(__expf(x));
}

// ---------------------------------------------------------------------------
// fp32 -> bf16 conversion (n multiple of 4)
// ---------------------------------------------------------------------------
__global__ __launch_bounds__(256) void cvt_bf16(
    const float* __restrict__ src, unsigned short* __restrict__ dst, int n)
{
    const int i = (blockIdx.x * 256 + threadIdx.x) * 4;
    if (i < n) {
        const float4 v = *(const float4*)(src + i);
        ushort4 o;
        o.x = f2bf(v.x); o.y = f2bf(v.y); o.z = f2bf(v.z); o.w = f2bf(v.w);
        *(ushort4*)(dst + i) = o;
    }
}

// ---------------------------------------------------------------------------
// bf16 MFMA GEMM:  C[M,N] = A[M,K](bf16) @ B[N,K](bf16)^T, fp32 accumulate.
// 128x128 tile, BK=64, 4 waves each owning a 64x64 region (4x4 frags of
// 16x16x32). LDS layout K-outer: tile[kb][128 rows][8 bf16] (kb = K/8 chunk),
// staged with global_load_lds width=16 (LDS dst = uniform base + lane*16).
// Fragment ds_read_b128: bank depth = 8 dwords/bank = b128 floor (no swizzle
// needed). M, N, K multiples of 128/128/64 required (true for all call sites).
// mode 1: softplus(c + bias[col]) epilogue.
// ---------------------------------------------------------------------------
__global__ __launch_bounds__(256) void gemm_bf16(
    const unsigned short* __restrict__ A, int lda,
    const unsigned short* __restrict__ B, int ldb,
    float* __restrict__ C, int ldc,
    int K, const float* __restrict__ bias, int mode)
{
    __shared__ unsigned short As[8][128 * 8];   // 16 KB
    __shared__ unsigned short Bs[8][128 * 8];   // 16 KB

    const int tid  = threadIdx.x;
    const int lane = tid & 63;
    const int w    = tid >> 6;       // wave 0..3
    const int wr   = w >> 1;         // wave row (0..1)
    const int wc   = w & 1;          // wave col (0..1)
    const int q    = lane >> 4;      // quad 0..3
    const int m    = lane & 15;
    const int row0 = blockIdx.y * 128;
    const int col0 = blockIdx.x * 128;

    f32x4 acc[4][4];
#pragma unroll
    for (int i = 0; i < 4; i++)
#pragma unroll
        for (int j = 0; j < 4; j++) acc[i][j] = (f32x4){0.f, 0.f, 0.f, 0.f};

    for (int k0 = 0; k0 < K; k0 += 64) {
        // stage A and B tiles: 16 chunks each of 1 KB; wave w does chunks
        // w*4..w*4+3. chunk c: kb = c>>1, half = c&1, row = half*64 + lane.
#pragma unroll
        for (int i = 0; i < 4; i++) {
            const int c    = w * 4 + i;
            const int kb   = c >> 1;
            const int half = c & 1;
            const unsigned short* ga =
                A + (size_t)(row0 + half * 64 + lane) * lda + k0 + kb * 8;
            const unsigned short* gb =
                B + (size_t)(col0 + half * 64 + lane) * ldb + k0 + kb * 8;
            __builtin_amdgcn_global_load_lds(
                (const __attribute__((address_space(1))) unsigned int*)ga,
                (__attribute__((address_space(3))) unsigned int*)&As[kb][half * 512],
                16, 0, 0);
            __builtin_amdgcn_global_load_lds(
                (const __attribute__((address_space(1))) unsigned int*)gb,
                (__attribute__((address_space(3))) unsigned int*)&Bs[kb][half * 512],
                16, 0, 0);
        }
        __syncthreads();

#pragma unroll
        for (int dep = 0; dep < 2; dep++) {
            bf16x8 af[4], bfr[4];
#pragma unroll
            for (int t = 0; t < 4; t++) {
                af[t]  = *(const bf16x8*)&As[dep * 4 + q][(wr * 64 + t * 16 + m) * 8];
                bfr[t] = *(const bf16x8*)&Bs[dep * 4 + q][(wc * 64 + t * 16 + m) * 8];
            }
#pragma unroll
            for (int mt = 0; mt < 4; mt++)
#pragma unroll
                for (int nt = 0; nt < 4; nt++)
                    acc[mt][nt] = __builtin_amdgcn_mfma_f32_16x16x32_bf16(
                        af[mt], bfr[nt], acc[mt][nt], 0, 0, 0);
        }
        __syncthreads();
    }

    // epilogue: D row = wr*64 + mt*16 + q*4 + r, col = wc*64 + nt*16 + m
#pragma unroll
    for (int mt = 0; mt < 4; mt++) {
#pragma unroll
        for (int nt = 0; nt < 4; nt++) {
            const int col = col0 + wc * 64 + nt * 16 + m;
            float bcol = 0.f;
            if (mode == 1) bcol = bias[col];
#pragma unroll
            for (int r = 0; r < 4; r++) {
                const int row = row0 + wr * 64 + mt * 16 + q * 4 + r;
                float v = acc[mt][nt][r];
                if (mode == 1) v = softplus_f(v + bcol);
                C[(size_t)row * ldc + col] = v;
            }
        }
    }
}

// ---------------------------------------------------------------------------
// Causal depthwise conv1d (K=4, left-pad 3) + bias + SiLU.
// ---------------------------------------------------------------------------
__global__ __launch_bounds__(256) void conv_silu_kernel(
    const float* __restrict__ xz,
    const float* __restrict__ conv_w,   // [D_INNER][1][4]
    const float* __restrict__ conv_b,
    float* __restrict__ xc)
{
    const int idx = blockIdx.x * 256 + threadIdx.x;   // over NROW*D_INNER
    const int d  = idx & (D_INNER - 1);
    const int rt = idx >> 11;                          // row = b*L + t
    const int t  = rt & (L_SEQ - 1);

    const float w0 = conv_w[d * 4 + 0];
    const float w1 = conv_w[d * 4 + 1];
    const float w2 = conv_w[d * 4 + 2];
    const float w3 = conv_w[d * 4 + 3];

    const float* col = xz + d;
    float acc = conv_b[d];
    if (t >= 3) acc = fmaf(w0, col[(size_t)(rt - 3) * (2 * D_INNER)], acc);
    if (t >= 2) acc = fmaf(w1, col[(size_t)(rt - 2) * (2 * D_INNER)], acc);
    if (t >= 1) acc = fmaf(w2, col[(size_t)(rt - 1) * (2 * D_INNER)], acc);
    acc = fmaf(w3, col[(size_t)rt * (2 * D_INNER)], acc);
    const float sig = 1.f / (1.f + __expf(-acc));
    xc[idx] = acc * sig;
}

// ---------------------------------------------------------------------------
// GEMM3 (skinny): x_dbl = xc[4096,2048] @ x_proj_w[96,2048]^T, split-K x16.
// Each chunk z covers K in [z*128, z*128+128); partials to Cp[z][4096][96].
// ---------------------------------------------------------------------------
#define G3_CHUNKS 16
#define G3_KCH    (2048 / G3_CHUNKS)   // 128

__global__ __launch_bounds__(256) void gemm3_splitk(
    const float* __restrict__ A,    // xc [4096][2048]
    const float* __restrict__ B,    // x_proj_w [96][2048]
    float* __restrict__ Cp)         // [16][4096][96]
{
    __shared__ float As[16][128];
    __shared__ float Bs[16][128];
    const int tid  = threadIdx.x;
    const int row0 = blockIdx.y * 128;
    const int tm = tid >> 4;
    const int tn = tid & 15;
    const int lr = tid >> 1;
    const int lc = (tid & 1) * 8;
    const int kbase = blockIdx.z * G3_KCH;

    float acc[8][8];
#pragma unroll
    for (int i = 0; i < 8; i++)
#pragma unroll
        for (int j = 0; j < 8; j++) acc[i][j] = 0.f;

    for (int k0 = kbase; k0 < kbase + G3_KCH; k0 += 16) {
        const float* ap = A + (size_t)(row0 + lr) * 2048 + k0 + lc;
        float4 a0 = *(const float4*)(ap);
        float4 a1 = *(const float4*)(ap + 4);
        float4 b0 = make_float4(0.f, 0.f, 0.f, 0.f);
        float4 b1 = make_float4(0.f, 0.f, 0.f, 0.f);
        if (lr < 96) {
            const float* bp = B + (size_t)lr * 2048 + k0 + lc;
            b0 = *(const float4*)(bp);
            b1 = *(const float4*)(bp + 4);
        }
        As[lc + 0][lr] = a0.x; As[lc + 1][lr] = a0.y;
        As[lc + 2][lr] = a0.z; As[lc + 3][lr] = a0.w;
        As[lc + 4][lr] = a1.x; As[lc + 5][lr] = a1.y;
        As[lc + 6][lr] = a1.z; As[lc + 7][lr] = a1.w;
        Bs[lc + 0][lr] = b0.x; Bs[lc + 1][lr] = b0.y;
        Bs[lc + 2][lr] = b0.z; Bs[lc + 3][lr] = b0.w;
        Bs[lc + 4][lr] = b1.x; Bs[lc + 5][lr] = b1.y;
        Bs[lc + 6][lr] = b1.z; Bs[lc + 7][lr] = b1.w;
        __syncthreads();

#pragma unroll
        for (int kk = 0; kk < 16; kk++) {
            float ar[8], br[8];
            *(float4*)&ar[0] = *(const float4*)&As[kk][tm * 8];
            *(float4*)&ar[4] = *(const float4*)&As[kk][tm * 8 + 4];
            *(float4*)&br[0] = *(const float4*)&Bs[kk][tn * 8];
            *(float4*)&br[4] = *(const float4*)&Bs[kk][tn * 8 + 4];
#pragma unroll
            for (int i = 0; i < 8; i++)
#pragma unroll
                for (int j = 0; j < 8; j++)
                    acc[i][j] = fmaf(ar[i], br[j], acc[i][j]);
        }
        __syncthreads();
    }

    float* Cz = Cp + (size_t)blockIdx.z * NROW * 96;
#pragma unroll
    for (int i = 0; i < 8; i++) {
        const int row = row0 + tm * 8 + i;
#pragma unroll
        for (int jj = 0; jj < 2; jj++) {
            const int col = tn * 8 + jj * 4;
            if (col < 96) {
                float4 v;
                v.x = acc[i][jj * 4 + 0];
                v.y = acc[i][jj * 4 + 1];
                v.z = acc[i][jj * 4 + 2];
                v.w = acc[i][jj * 4 + 3];
                *(float4*)(Cz + (size_t)row * 96 + col) = v;
            }
        }
    }
}

__global__ __launch_bounds__(256) void reduce3(
    const float* __restrict__ Cp,
    float* __restrict__ xdbl,
    unsigned short* __restrict__ xdbl_bf)
{
    const int idx = blockIdx.x * 256 + threadIdx.x;   // < 4096*96
    float s = 0.f;
#pragma unroll
    for (int z = 0; z < G3_CHUNKS; z++)
        s += Cp[(size_t)z * NROW * 96 + idx];
    xdbl[idx] = s;
    xdbl_bf[idx] = f2bf(s);
}

// ---------------------------------------------------------------------------
// Chunked parallel selective scan (pass3 emits y in bf16 for out_proj).
// ---------------------------------------------------------------------------
#define T_CH    64
#define G_CHUNK 8
#define T_CHUNK (L_SEQ / G_CHUNK)   // 256

__global__ __launch_bounds__(256) void scan_pass1(
    const float* __restrict__ dtbuf,   // [NROW][D_INNER]
    const float* __restrict__ xc,      // [NROW][D_INNER]
    const float* __restrict__ xdbl,    // [NROW][96]: [64,80)=B
    const float* __restrict__ A_log,   // [D_INNER][16]
    float* __restrict__ aprod,         // [G][B][D_INNER][16]
    float* __restrict__ hend)          // [G][B][D_INNER][16]
{
    __shared__ float dt_s[T_CH][16], x_s[T_CH][16], B_s[T_CH][16];

    const int tid = threadIdx.x;
    const int dl  = tid >> 4;
    const int n   = tid & 15;
    const int blk = blockIdx.x;
    const int g   = blk & (G_CHUNK - 1);
    const int db  = (blk >> 3) & 127;
    const int b   = blk >> 10;
    const int d0  = db << 4;
    const int d   = d0 + dl;

    const float A_dn = -expf(A_log[(size_t)d * D_STATE + n]);
    float h = 0.f, ap = 1.f;
    const size_t rowbase = (size_t)b * L_SEQ + (size_t)g * T_CHUNK;

    for (int t0 = 0; t0 < T_CHUNK; t0 += T_CH) {
#pragma unroll
        for (int i = 0; i < 4; i++) {
            const int idx = i * 256 + tid;
            const int tt = idx >> 4;
            const int j  = idx & 15;
            const size_t r = rowbase + t0 + tt;
            dt_s[tt][j] = dtbuf[r * D_INNER + d0 + j];
            x_s[tt][j]  = xc[r * D_INNER + d0 + j];
            B_s[tt][j]  = xdbl[r * 96 + DT_RANK + j];
        }
        __syncthreads();

#pragma unroll 8
        for (int tt = 0; tt < T_CH; tt++) {
            const float dtv = dt_s[tt][dl];
            const float xv  = x_s[tt][dl];
            const float dA  = __expf(dtv * A_dn);
            ap *= dA;
            h = fmaf(dA, h, dtv * xv * B_s[tt][n]);
        }
        __syncthreads();
    }

    const size_t o = (((size_t)g * B_SZ + b) * D_INNER + d) * D_STATE + n;
    aprod[o] = ap;
    hend[o]  = h;
}

__global__ __launch_bounds__(256) void scan_pass2(
    const float* __restrict__ aprod,
    const float* __restrict__ hend,
    float* __restrict__ H0)
{
    const int idx = blockIdx.x * 256 + threadIdx.x;   // over B*D_INNER*16
    const size_t stride = (size_t)B_SZ * D_INNER * D_STATE;
    float h = 0.f;
#pragma unroll
    for (int g = 0; g < G_CHUNK; g++) {
        H0[(size_t)g * stride + idx] = h;
        h = fmaf(aprod[(size_t)g * stride + idx], h, hend[(size_t)g * stride + idx]);
    }
}

__global__ __launch_bounds__(256) void scan_pass3(
    const float* __restrict__ dtbuf,
    const float* __restrict__ xc,
    const float* __restrict__ xz,      // z at +D_INNER
    const float* __restrict__ xdbl,
    const float* __restrict__ A_log,
    const float* __restrict__ Dvec,
    const float* __restrict__ H0,
    unsigned short* __restrict__ y)    // [NROW][D_INNER] bf16
{
    __shared__ float dt_s[T_CH][16], x_s[T_CH][16], z_s[T_CH][16];
    __shared__ float B_s[T_CH][16], C_s[T_CH][16], y_s[T_CH][16];

    const int tid = threadIdx.x;
    const int dl  = tid >> 4;
    const int n   = tid & 15;
    const int blk = blockIdx.x;
    const int g   = blk & (G_CHUNK - 1);
    const int db  = (blk >> 3) & 127;
    const int b   = blk >> 10;
    const int d0  = db << 4;
    const int d   = d0 + dl;

    const float A_dn = -expf(A_log[(size_t)d * D_STATE + n]);
    const float D_d  = Dvec[d];
    float h = H0[(((size_t)g * B_SZ + b) * D_INNER + d) * D_STATE + n];
    const size_t rowbase = (size_t)b * L_SEQ + (size_t)g * T_CHUNK;

    for (int t0 = 0; t0 < T_CHUNK; t0 += T_CH) {
#pragma unroll
        for (int i = 0; i < 4; i++) {
            const int idx = i * 256 + tid;
            const int tt = idx >> 4;
            const int j  = idx & 15;
            const size_t r = rowbase + t0 + tt;
            dt_s[tt][j] = dtbuf[r * D_INNER + d0 + j];
            x_s[tt][j]  = xc[r * D_INNER + d0 + j];
            z_s[tt][j]  = xz[r * (2 * D_INNER) + D_INNER + d0 + j];
            B_s[tt][j]  = xdbl[r * 96 + DT_RANK + j];
            C_s[tt][j]  = xdbl[r * 96 + DT_RANK + D_STATE + j];
        }
        __syncthreads();

        for (int tt = 0; tt < T_CH; tt++) {
            const float dtv = dt_s[tt][dl];
            const float xv  = x_s[tt][dl];
            const float dA  = __expf(dtv * A_dn);
            h = fmaf(dA, h, dtv * xv * B_s[tt][n]);
            float p = h * C_s[tt][n];
            p += __shfl_xor(p, 1, 16);
            p += __shfl_xor(p, 2, 16);
            p += __shfl_xor(p, 4, 16);
            p += __shfl_xor(p, 8, 16);
            if (n == 0) {
                const float zv  = z_s[tt][dl];
                const float sig = 1.f / (1.f + __expf(-zv));
                y_s[tt][dl] = (p + D_d * xv) * (zv * sig);
            }
        }
        __syncthreads();

#pragma unroll
        for (int i = 0; i < 4; i++) {
            const int idx = i * 256 + tid;
            const int tt = idx >> 4;
            const int j  = idx & 15;
            const size_t r = rowbase + t0 + tt;
            y[r * D_INNER + d0 + j] = f2bf(y_s[tt][j]);
        }
        __syncthreads();
    }
}

// ---------------------------------------------------------------------------
extern "C" void kernel_launch(void* const* d_in, const int* in_sizes, int n_in,
                              void* d_out, int out_size, void* d_ws, size_t ws_size,
                              hipStream_t stream) {
    const float* x          = (const float*)d_in[0];
    const float* in_proj_w  = (const float*)d_in[1];
    const float* conv_w     = (const float*)d_in[2];
    const float* conv_b     = (const float*)d_in[3];
    const float* x_proj_w   = (const float*)d_in[4];
    const float* dt_proj_w  = (const float*)d_in[5];
    const float* dt_proj_b  = (const float*)d_in[6];
    const float* A_log      = (const float*)d_in[7];
    const float* Dv         = (const float*)d_in[8];
    const float* out_proj_w = (const float*)d_in[9];
    float* out = (float*)d_out;

    // workspace layout (fp32 region then bf16 region); aliases noted
    float* ws   = (float*)d_ws;
    float* xz   = ws;                                    // 16,777,216 f
    float* xc   = xz   + (size_t)NROW * 2 * D_INNER;     //  8,388,608 f
    float* xdbl = xc   + (size_t)NROW * D_INNER;         //    393,216 f
    float* dtb  = xdbl + (size_t)NROW * 96;              //  8,388,608 f
    float* apr  = dtb  + (size_t)NROW * D_INNER;         //    524,288 f
    float* hen  = apr  + (size_t)G_CHUNK * B_SZ * D_INNER * D_STATE;
    float* H0   = hen  + (size_t)G_CHUNK * B_SZ * D_INNER * D_STATE;
    unsigned short* yb_bf   = (unsigned short*)(H0 + (size_t)G_CHUNK * B_SZ * D_INNER * D_STATE); // 8,388,608 us
    unsigned short* dtw_bf  = yb_bf  + (size_t)NROW * D_INNER;   // 131,072 us
    unsigned short* outw_bf = dtw_bf + (size_t)D_INNER * DT_RANK; // 2,097,152 us
    unsigned short* xdbl_bf = outw_bf + (size_t)D_MODEL * D_INNER; // 393,216 us
    // aliases (non-overlapping lifetimes):
    unsigned short* x_bf   = (unsigned short*)dtb;   // steps 1-2 only; dtb written step 6
    unsigned short* inw_bf = yb_bf;                  // steps 1-2 only; yb written step 7
    float* Cp = dtb;                                 // steps 4-5 only (16*393216 f < dtb+apr.. fits in dtb? 6.29M < 8.39M yes)

    dim3 blk(256);

    // 0) fp32 -> bf16 conversions
    cvt_bf16<<<dim3((NROW * D_MODEL) / 1024), blk, 0, stream>>>(x, x_bf, NROW * D_MODEL);
    cvt_bf16<<<dim3((2 * D_INNER * D_MODEL) / 1024), blk, 0, stream>>>(in_proj_w, inw_bf, 2 * D_INNER * D_MODEL);
    cvt_bf16<<<dim3((D_INNER * DT_RANK) / 1024), blk, 0, stream>>>(dt_proj_w, dtw_bf, D_INNER * DT_RANK);
    cvt_bf16<<<dim3((D_MODEL * D_INNER) / 1024), blk, 0, stream>>>(out_proj_w, outw_bf, D_MODEL * D_INNER);

    // 1) xz = x @ in_proj_w^T   (M=4096, N=4096, K=1024) bf16 MFMA
    gemm_bf16<<<dim3((2 * D_INNER) / 128, NROW / 128), blk, 0, stream>>>(
        x_bf, D_MODEL, inw_bf, D_MODEL, xz, 2 * D_INNER, D_MODEL, nullptr, 0);

    // 2) causal depthwise conv + bias + SiLU -> xc (fp32)
    conv_silu_kernel<<<dim3((NROW * D_INNER) / 256), blk, 0, stream>>>(
        xz, conv_w, conv_b, xc);

    // 3) x_dbl = xc @ x_proj_w^T (M=4096, N=96, K=2048) split-K fp32
    gemm3_splitk<<<dim3(1, NROW / 128, G3_CHUNKS), blk, 0, stream>>>(
        xc, x_proj_w, Cp);
    reduce3<<<dim3((NROW * 96) / 256), blk, 0, stream>>>(Cp, xdbl, xdbl_bf);

    // 4) dt = softplus(dt_r @ dt_proj_w^T + b) (M=4096, N=2048, K=64) bf16
    gemm_bf16<<<dim3(D_INNER / 128, NROW / 128), blk, 0, stream>>>(
        xdbl_bf, 96, dtw_bf, DT_RANK, dtb, D_INNER, DT_RANK, dt_proj_b, 1);

    // 5) chunked parallel selective scan -> yb (bf16)
    scan_pass1<<<dim3(B_SZ * (D_INNER / 16) * G_CHUNK), blk, 0, stream>>>(
        dtb, xc, xdbl, A_log, apr, hen);
    scan_pass2<<<dim3(B_SZ * D_INNER * D_STATE / 256), blk, 0, stream>>>(
        apr, hen, H0);
    scan_pass3<<<dim3(B_SZ * (D_INNER / 16) * G_CHUNK), blk, 0, stream>>>(
        dtb, xc, xz, xdbl, A_log, Dv, H0, yb_bf);

    // 6) out = y @ out_proj_w^T (M=4096, N=1024, K=2048) bf16 MFMA
    gemm_bf16<<<dim3(D_MODEL / 128, NROW / 128), blk, 0, stream>>>(
        yb_bf, D_INNER, outw_bf, D_INNER, out, D_MODEL, D_INNER, nullptr, 0);
}

// Round 4
// 410.467 us; speedup vs baseline: 3.9651x; 1.3200x over previous
//
#include <hip/hip_runtime.h>
#include <math.h>

#define D_MODEL 1024
#define D_STATE 16
#define D_CONV  4
#define D_INNER 2048
#define DT_RANK 64
#define B_SZ    2
#define L_SEQ   2048
#define NROW    (B_SZ * L_SEQ)   // 4096

typedef __bf16 bf16x8 __attribute__((ext_vector_type(8)));
typedef float  f32x4  __attribute__((ext_vector_type(4)));

__device__ __forceinline__ unsigned short f2bf(float f) {
    unsigned u = __float_as_uint(f);
    u += 0x7fff + ((u >> 16) & 1);       // RNE
    return (unsigned short)(u >> 16);
}

__device__ __forceinline__ float softplus_f(float x) {
    return (x > 20.f) ? x : log1pf(__expf(x));
}

// ---------------------------------------------------------------------------
// fp32 -> bf16 conversion (n multiple of 4)
// ---------------------------------------------------------------------------
__global__ __launch_bounds__(256) void cvt_bf16(
    const float* __restrict__ src, unsigned short* __restrict__ dst, int n)
{
    const int i = (blockIdx.x * 256 + threadIdx.x) * 4;
    if (i < n) {
        const float4 v = *(const float4*)(src + i);
        ushort4 o;
        o.x = f2bf(v.x); o.y = f2bf(v.y); o.z = f2bf(v.z); o.w = f2bf(v.w);
        *(ushort4*)(dst + i) = o;
    }
}

// x_proj_w [96][2048] -> bf16 padded to [128][2048] (rows 96..127 zero)
__global__ __launch_bounds__(256) void cvt_pad_xpw(
    const float* __restrict__ src, unsigned short* __restrict__ dst)
{
    const int i = (blockIdx.x * 256 + threadIdx.x) * 4;   // < 128*2048
    const int row = i >> 11;
    ushort4 o = make_ushort4(0, 0, 0, 0);
    if (row < 96) {
        const float4 v = *(const float4*)(src + (size_t)row * 2048 + (i & 2047));
        o.x = f2bf(v.x); o.y = f2bf(v.y); o.z = f2bf(v.z); o.w = f2bf(v.w);
    }
    *(ushort4*)(dst + i) = o;
}

// ---------------------------------------------------------------------------
// bf16 MFMA GEMM:  C[M,N] = A[M,K](bf16) @ B[N,K](bf16)^T, fp32 accumulate.
// 128x128 tile, BK=64, 4 waves each owning a 64x64 region (4x4 frags of
// 16x16x32). K-outer LDS layout, staged with global_load_lds width=16.
// mode 1: softplus(c + bias[col]) epilogue.
// ---------------------------------------------------------------------------
__global__ __launch_bounds__(256) void gemm_bf16(
    const unsigned short* __restrict__ A, int lda,
    const unsigned short* __restrict__ B, int ldb,
    float* __restrict__ C, int ldc,
    int K, const float* __restrict__ bias, int mode)
{
    __shared__ unsigned short As[8][128 * 8];   // 16 KB
    __shared__ unsigned short Bs[8][128 * 8];   // 16 KB

    const int tid  = threadIdx.x;
    const int lane = tid & 63;
    const int w    = tid >> 6;
    const int wr   = w >> 1;
    const int wc   = w & 1;
    const int q    = lane >> 4;
    const int m    = lane & 15;
    const int row0 = blockIdx.y * 128;
    const int col0 = blockIdx.x * 128;

    f32x4 acc[4][4];
#pragma unroll
    for (int i = 0; i < 4; i++)
#pragma unroll
        for (int j = 0; j < 4; j++) acc[i][j] = (f32x4){0.f, 0.f, 0.f, 0.f};

    for (int k0 = 0; k0 < K; k0 += 64) {
#pragma unroll
        for (int i = 0; i < 4; i++) {
            const int c    = w * 4 + i;
            const int kb   = c >> 1;
            const int half = c & 1;
            const unsigned short* ga =
                A + (size_t)(row0 + half * 64 + lane) * lda + k0 + kb * 8;
            const unsigned short* gb =
                B + (size_t)(col0 + half * 64 + lane) * ldb + k0 + kb * 8;
            __builtin_amdgcn_global_load_lds(
                (const __attribute__((address_space(1))) unsigned int*)ga,
                (__attribute__((address_space(3))) unsigned int*)&As[kb][half * 512],
                16, 0, 0);
            __builtin_amdgcn_global_load_lds(
                (const __attribute__((address_space(1))) unsigned int*)gb,
                (__attribute__((address_space(3))) unsigned int*)&Bs[kb][half * 512],
                16, 0, 0);
        }
        __syncthreads();

#pragma unroll
        for (int dep = 0; dep < 2; dep++) {
            bf16x8 af[4], bfr[4];
#pragma unroll
            for (int t = 0; t < 4; t++) {
                af[t]  = *(const bf16x8*)&As[dep * 4 + q][(wr * 64 + t * 16 + m) * 8];
                bfr[t] = *(const bf16x8*)&Bs[dep * 4 + q][(wc * 64 + t * 16 + m) * 8];
            }
#pragma unroll
            for (int mt = 0; mt < 4; mt++)
#pragma unroll
                for (int nt = 0; nt < 4; nt++)
                    acc[mt][nt] = __builtin_amdgcn_mfma_f32_16x16x32_bf16(
                        af[mt], bfr[nt], acc[mt][nt], 0, 0, 0);
        }
        __syncthreads();
    }

#pragma unroll
    for (int mt = 0; mt < 4; mt++) {
#pragma unroll
        for (int nt = 0; nt < 4; nt++) {
            const int col = col0 + wc * 64 + nt * 16 + m;
            float bcol = 0.f;
            if (mode == 1) bcol = bias[col];
#pragma unroll
            for (int r = 0; r < 4; r++) {
                const int row = row0 + wr * 64 + mt * 16 + q * 4 + r;
                float v = acc[mt][nt][r];
                if (mode == 1) v = softplus_f(v + bcol);
                C[(size_t)row * ldc + col] = v;
            }
        }
    }
}

// ---------------------------------------------------------------------------
// GEMM3 bf16 split-K: x_dbl = xc_bf[4096,2048] @ xpw_pad[128,2048]^T.
// blockIdx.z = K-chunk (8 chunks of 256); partials to Cp[z][4096][96].
// ---------------------------------------------------------------------------
#define G3Z 8

__global__ __launch_bounds__(256) void gemm3_bf16_splitk(
    const unsigned short* __restrict__ A,   // [4096][2048]
    const unsigned short* __restrict__ B,   // [128][2048] padded
    float* __restrict__ Cp)                 // [G3Z][4096][96]
{
    __shared__ unsigned short As[8][128 * 8];
    __shared__ unsigned short Bs[8][128 * 8];

    const int tid  = threadIdx.x;
    const int lane = tid & 63;
    const int w    = tid >> 6;
    const int wr   = w >> 1;
    const int wc   = w & 1;
    const int q    = lane >> 4;
    const int m    = lane & 15;
    const int row0 = blockIdx.y * 128;
    const int kz0  = blockIdx.z * (2048 / G3Z);

    f32x4 acc[4][4];
#pragma unroll
    for (int i = 0; i < 4; i++)
#pragma unroll
        for (int j = 0; j < 4; j++) acc[i][j] = (f32x4){0.f, 0.f, 0.f, 0.f};

    for (int k0 = kz0; k0 < kz0 + (2048 / G3Z); k0 += 64) {
#pragma unroll
        for (int i = 0; i < 4; i++) {
            const int c    = w * 4 + i;
            const int kb   = c >> 1;
            const int half = c & 1;
            const unsigned short* ga =
                A + (size_t)(row0 + half * 64 + lane) * 2048 + k0 + kb * 8;
            const unsigned short* gb =
                B + (size_t)(half * 64 + lane) * 2048 + k0 + kb * 8;
            __builtin_amdgcn_global_load_lds(
                (const __attribute__((address_space(1))) unsigned int*)ga,
                (__attribute__((address_space(3))) unsigned int*)&As[kb][half * 512],
                16, 0, 0);
            __builtin_amdgcn_global_load_lds(
                (const __attribute__((address_space(1))) unsigned int*)gb,
                (__attribute__((address_space(3))) unsigned int*)&Bs[kb][half * 512],
                16, 0, 0);
        }
        __syncthreads();

#pragma unroll
        for (int dep = 0; dep < 2; dep++) {
            bf16x8 af[4], bfr[4];
#pragma unroll
            for (int t = 0; t < 4; t++) {
                af[t]  = *(const bf16x8*)&As[dep * 4 + q][(wr * 64 + t * 16 + m) * 8];
                bfr[t] = *(const bf16x8*)&Bs[dep * 4 + q][(wc * 64 + t * 16 + m) * 8];
            }
#pragma unroll
            for (int mt = 0; mt < 4; mt++)
#pragma unroll
                for (int nt = 0; nt < 4; nt++)
                    acc[mt][nt] = __builtin_amdgcn_mfma_f32_16x16x32_bf16(
                        af[mt], bfr[nt], acc[mt][nt], 0, 0, 0);
        }
        __syncthreads();
    }

    float* Cz = Cp + (size_t)blockIdx.z * NROW * 96;
#pragma unroll
    for (int mt = 0; mt < 4; mt++) {
#pragma unroll
        for (int nt = 0; nt < 4; nt++) {
            const int col = wc * 64 + nt * 16 + m;
            if (col < 96) {
#pragma unroll
                for (int r = 0; r < 4; r++) {
                    const int row = row0 + wr * 64 + mt * 16 + q * 4 + r;
                    Cz[(size_t)row * 96 + col] = acc[mt][nt][r];
                }
            }
        }
    }
}

__global__ __launch_bounds__(256) void reduce3(
    const float* __restrict__ Cp,
    float* __restrict__ xdbl,
    unsigned short* __restrict__ xdbl_bf)
{
    const int idx = blockIdx.x * 256 + threadIdx.x;   // < 4096*96
    float s = 0.f;
#pragma unroll
    for (int z = 0; z < G3Z; z++)
        s += Cp[(size_t)z * NROW * 96 + idx];
    xdbl[idx] = s;
    xdbl_bf[idx] = f2bf(s);
}

// ---------------------------------------------------------------------------
// Causal depthwise conv1d (K=4, left-pad 3) + bias + SiLU; fp32 + bf16 out.
// ---------------------------------------------------------------------------
__global__ __launch_bounds__(256) void conv_silu_kernel(
    const float* __restrict__ xz,
    const float* __restrict__ conv_w,
    const float* __restrict__ conv_b,
    float* __restrict__ xc,
    unsigned short* __restrict__ xc_bf)
{
    const int idx = blockIdx.x * 256 + threadIdx.x;   // over NROW*D_INNER
    const int d  = idx & (D_INNER - 1);
    const int rt = idx >> 11;
    const int t  = rt & (L_SEQ - 1);

    const float w0 = conv_w[d * 4 + 0];
    const float w1 = conv_w[d * 4 + 1];
    const float w2 = conv_w[d * 4 + 2];
    const float w3 = conv_w[d * 4 + 3];

    const float* col = xz + d;
    float acc = conv_b[d];
    if (t >= 3) acc = fmaf(w0, col[(size_t)(rt - 3) * (2 * D_INNER)], acc);
    if (t >= 2) acc = fmaf(w1, col[(size_t)(rt - 2) * (2 * D_INNER)], acc);
    if (t >= 1) acc = fmaf(w2, col[(size_t)(rt - 1) * (2 * D_INNER)], acc);
    acc = fmaf(w3, col[(size_t)rt * (2 * D_INNER)], acc);
    const float sig = 1.f / (1.f + __expf(-acc));
    const float v = acc * sig;
    xc[idx] = v;
    xc_bf[idx] = f2bf(v);
}

// ---------------------------------------------------------------------------
// Chunked parallel selective scan, thread-per-d with h[16] in registers.
//   pass1: per chunk g (len 64), local h_end[16] and aprod[16] (h0=0)
//   pass2: sequential combine over G=32 chunks -> H0
//   pass3: re-run chunk from H0, emit y = (h.C + D*x)*silu(z) as bf16
// State layout n-major for coalescing: [g][b][n][d].
// ---------------------------------------------------------------------------
#define G_CHUNK 32
#define T_CHUNK (L_SEQ / G_CHUNK)   // 64

__global__ __launch_bounds__(256) void scan_pass1(
    const float* __restrict__ dtbuf,   // [NROW][D_INNER]
    const float* __restrict__ xc,      // [NROW][D_INNER]
    const float* __restrict__ xdbl,    // [NROW][96]: [64,80)=B
    const float* __restrict__ A_log,   // [D_INNER][16]
    float* __restrict__ aprod,         // [G][B][16][D_INNER]
    float* __restrict__ hend)          // [G][B][16][D_INNER]
{
    __shared__ float B_s[T_CHUNK][16];

    const int tid = threadIdx.x;
    const int g   = blockIdx.x;
    const int db  = blockIdx.y;        // 0..15
    const int b   = db >> 3;
    const int d   = (db & 7) * 256 + tid;
    const size_t rowbase = (size_t)b * L_SEQ + (size_t)g * T_CHUNK;

    {   // stage B chunk: 64 rows x 16 floats
        const int tt = tid >> 2, q4 = (tid & 3) * 4;
        *(float4*)&B_s[tt][q4] =
            *(const float4*)&xdbl[(rowbase + tt) * 96 + DT_RANK + q4];
    }

    float A_dn[16];
#pragma unroll
    for (int n = 0; n < 16; n++)
        A_dn[n] = -expf(A_log[(size_t)d * D_STATE + n]);

    float h[16], ap[16];
#pragma unroll
    for (int n = 0; n < 16; n++) { h[n] = 0.f; ap[n] = 1.f; }

    __syncthreads();

#pragma unroll 2
    for (int t = 0; t < T_CHUNK; t++) {
        const size_t r = rowbase + t;
        const float dtv = dtbuf[r * D_INNER + d];
        const float xv  = xc[r * D_INNER + d];
        const float dtx = dtv * xv;
        float Bv[16];
        *(float4*)&Bv[0]  = *(const float4*)&B_s[t][0];
        *(float4*)&Bv[4]  = *(const float4*)&B_s[t][4];
        *(float4*)&Bv[8]  = *(const float4*)&B_s[t][8];
        *(float4*)&Bv[12] = *(const float4*)&B_s[t][12];
#pragma unroll
        for (int n = 0; n < 16; n++) {
            const float dA = __expf(dtv * A_dn[n]);
            ap[n] *= dA;
            h[n] = fmaf(dA, h[n], dtx * Bv[n]);
        }
    }

    const size_t base = ((size_t)g * B_SZ + b) * D_STATE * D_INNER + d;
#pragma unroll
    for (int n = 0; n < 16; n++) {
        aprod[base + (size_t)n * D_INNER] = ap[n];
        hend[base + (size_t)n * D_INNER]  = h[n];
    }
}

__global__ __launch_bounds__(256) void scan_pass2(
    const float* __restrict__ aprod,
    const float* __restrict__ hend,
    float* __restrict__ H0)
{
    const int idx = blockIdx.x * 256 + threadIdx.x;   // over B*16*D_INNER
    const size_t stride = (size_t)B_SZ * D_STATE * D_INNER;
    float h = 0.f;
#pragma unroll
    for (int g = 0; g < G_CHUNK; g++) {
        H0[(size_t)g * stride + idx] = h;
        h = fmaf(aprod[(size_t)g * stride + idx], h, hend[(size_t)g * stride + idx]);
    }
}

__global__ __launch_bounds__(256) void scan_pass3(
    const float* __restrict__ dtbuf,
    const float* __restrict__ xc,
    const float* __restrict__ xz,      // z at +D_INNER
    const float* __restrict__ xdbl,
    const float* __restrict__ A_log,
    const float* __restrict__ Dvec,
    const float* __restrict__ H0,      // [G][B][16][D_INNER]
    unsigned short* __restrict__ y)    // [NROW][D_INNER] bf16
{
    __shared__ float B_s[T_CHUNK][16];
    __shared__ float C_s[T_CHUNK][16];

    const int tid = threadIdx.x;
    const int g   = blockIdx.x;
    const int db  = blockIdx.y;
    const int b   = db >> 3;
    const int d   = (db & 7) * 256 + tid;
    const size_t rowbase = (size_t)b * L_SEQ + (size_t)g * T_CHUNK;

    {
        const int tt = tid >> 2, q4 = (tid & 3) * 4;
        *(float4*)&B_s[tt][q4] =
            *(const float4*)&xdbl[(rowbase + tt) * 96 + DT_RANK + q4];
        *(float4*)&C_s[tt][q4] =
            *(const float4*)&xdbl[(rowbase + tt) * 96 + DT_RANK + D_STATE + q4];
    }

    float A_dn[16];
#pragma unroll
    for (int n = 0; n < 16; n++)
        A_dn[n] = -expf(A_log[(size_t)d * D_STATE + n]);
    const float D_d = Dvec[d];

    float h[16];
    const size_t base = ((size_t)g * B_SZ + b) * D_STATE * D_INNER + d;
#pragma unroll
    for (int n = 0; n < 16; n++)
        h[n] = H0[base + (size_t)n * D_INNER];

    __syncthreads();

#pragma unroll 2
    for (int t = 0; t < T_CHUNK; t++) {
        const size_t r = rowbase + t;
        const float dtv = dtbuf[r * D_INNER + d];
        const float xv  = xc[r * D_INNER + d];
        const float zv  = xz[r * (2 * D_INNER) + D_INNER + d];
        const float dtx = dtv * xv;
        float Bv[16], Cv[16];
        *(float4*)&Bv[0]  = *(const float4*)&B_s[t][0];
        *(float4*)&Bv[4]  = *(const float4*)&B_s[t][4];
        *(float4*)&Bv[8]  = *(const float4*)&B_s[t][8];
        *(float4*)&Bv[12] = *(const float4*)&B_s[t][12];
        *(float4*)&Cv[0]  = *(const float4*)&C_s[t][0];
        *(float4*)&Cv[4]  = *(const float4*)&C_s[t][4];
        *(float4*)&Cv[8]  = *(const float4*)&C_s[t][8];
        *(float4*)&Cv[12] = *(const float4*)&C_s[t][12];
        float dot = 0.f;
#pragma unroll
        for (int n = 0; n < 16; n++) {
            const float dA = __expf(dtv * A_dn[n]);
            h[n] = fmaf(dA, h[n], dtx * Bv[n]);
            dot = fmaf(h[n], Cv[n], dot);
        }
        const float sig = 1.f / (1.f + __expf(-zv));
        const float yv = (dot + D_d * xv) * (zv * sig);
        y[r * D_INNER + d] = f2bf(yv);
    }
}

// ---------------------------------------------------------------------------
extern "C" void kernel_launch(void* const* d_in, const int* in_sizes, int n_in,
                              void* d_out, int out_size, void* d_ws, size_t ws_size,
                              hipStream_t stream) {
    const float* x          = (const float*)d_in[0];
    const float* in_proj_w  = (const float*)d_in[1];
    const float* conv_w     = (const float*)d_in[2];
    const float* conv_b     = (const float*)d_in[3];
    const float* x_proj_w   = (const float*)d_in[4];
    const float* dt_proj_w  = (const float*)d_in[5];
    const float* dt_proj_b  = (const float*)d_in[6];
    const float* A_log      = (const float*)d_in[7];
    const float* Dv         = (const float*)d_in[8];
    const float* out_proj_w = (const float*)d_in[9];
    float* out = (float*)d_out;

    float* ws   = (float*)d_ws;
    float* xz   = ws;                                  // 16,777,216 f
    float* xc   = xz   + (size_t)16777216;             //  8,388,608 f
    float* xdbl = xc   + (size_t)8388608;              //    393,216 f
    float* dtb  = xdbl + (size_t)393216;               //  8,388,608 f
    float* apr  = dtb  + (size_t)8388608;              //  2,097,152 f
    float* hen  = apr  + (size_t)2097152;              //  2,097,152 f
    float* H0   = hen  + (size_t)2097152;              //  2,097,152 f
    unsigned short* yb_bf   = (unsigned short*)(H0 + 2097152);     // 8,388,608 us
    unsigned short* xc_bf   = yb_bf   + (size_t)8388608;           // 8,388,608 us
    unsigned short* dtw_bf  = xc_bf   + (size_t)8388608;           //   131,072 us
    unsigned short* outw_bf = dtw_bf  + (size_t)131072;            // 2,097,152 us
    unsigned short* xdbl_bf = outw_bf + (size_t)2097152;           //   393,216 us
    unsigned short* xpw_bf  = xdbl_bf + (size_t)393216;            //   262,144 us
    // aliases (disjoint lifetimes / regions inside dtb, written at step 4):
    unsigned short* x_bf   = (unsigned short*)dtb;        // steps 0-1 (2.1M f)
    float*          Cp     = dtb + 2097152;               // step 3 (3.15M f)
    unsigned short* inw_bf = yb_bf;                       // steps 0-1

    dim3 blk(256);

    // 0) conversions
    cvt_bf16<<<dim3(4096), blk, 0, stream>>>(x, x_bf, NROW * D_MODEL);
    cvt_bf16<<<dim3(4096), blk, 0, stream>>>(in_proj_w, inw_bf, 2 * D_INNER * D_MODEL);
    cvt_bf16<<<dim3(128),  blk, 0, stream>>>(dt_proj_w, dtw_bf, D_INNER * DT_RANK);
    cvt_bf16<<<dim3(2048), blk, 0, stream>>>(out_proj_w, outw_bf, D_MODEL * D_INNER);
    cvt_pad_xpw<<<dim3(256), blk, 0, stream>>>(x_proj_w, xpw_bf);

    // 1) xz = x @ in_proj_w^T   (M=4096, N=4096, K=1024)
    gemm_bf16<<<dim3(32, 32), blk, 0, stream>>>(
        x_bf, D_MODEL, inw_bf, D_MODEL, xz, 2 * D_INNER, D_MODEL, nullptr, 0);

    // 2) conv + bias + SiLU -> xc (fp32) + xc_bf
    conv_silu_kernel<<<dim3((NROW * D_INNER) / 256), blk, 0, stream>>>(
        xz, conv_w, conv_b, xc, xc_bf);

    // 3) x_dbl = xc @ x_proj_w^T (split-K bf16)
    gemm3_bf16_splitk<<<dim3(1, 32, G3Z), blk, 0, stream>>>(xc_bf, xpw_bf, Cp);
    reduce3<<<dim3((NROW * 96) / 256), blk, 0, stream>>>(Cp, xdbl, xdbl_bf);

    // 4) dt = softplus(dt_r @ dt_proj_w^T + b)  (M=4096, N=2048, K=64)
    gemm_bf16<<<dim3(16, 32), blk, 0, stream>>>(
        xdbl_bf, 96, dtw_bf, DT_RANK, dtb, D_INNER, DT_RANK, dt_proj_b, 1);

    // 5) chunked parallel selective scan -> yb (bf16)
    scan_pass1<<<dim3(G_CHUNK, 16), blk, 0, stream>>>(
        dtb, xc, xdbl, A_log, apr, hen);
    scan_pass2<<<dim3(B_SZ * D_STATE * D_INNER / 256), blk, 0, stream>>>(
        apr, hen, H0);
    scan_pass3<<<dim3(G_CHUNK, 16), blk, 0, stream>>>(
        dtb, xc, xz, xdbl, A_log, Dv, H0, yb_bf);

    // 6) out = y @ out_proj_w^T  (M=4096, N=1024, K=2048)
    gemm_bf16<<<dim3(8, 32), blk, 0, stream>>>(
        yb_bf, D_INNER, outw_bf, D_INNER, out, D_MODEL, D_INNER, nullptr, 0);
}

// Round 5
// 401.641 us; speedup vs baseline: 4.0522x; 1.0220x over previous
//
#include <hip/hip_runtime.h>
#include <math.h>

#define D_MODEL 1024
#define D_STATE 16
#define D_CONV  4
#define D_INNER 2048
#define DT_RANK 64
#define B_SZ    2
#define L_SEQ   2048
#define NROW    (B_SZ * L_SEQ)   // 4096

typedef __bf16 bf16x8 __attribute__((ext_vector_type(8)));
typedef float  f32x4  __attribute__((ext_vector_type(4)));
typedef unsigned short ushort8 __attribute__((ext_vector_type(8)));

__device__ __forceinline__ unsigned short f2bf(float f) {
    unsigned u = __float_as_uint(f);
    u += 0x7fff + ((u >> 16) & 1);       // RNE
    return (unsigned short)(u >> 16);
}
__device__ __forceinline__ float bf2f(unsigned short v) {
    return __uint_as_float((unsigned)v << 16);
}
__device__ __forceinline__ float softplus_f(float x) {
    return (x > 20.f) ? x : log1pf(__expf(x));
}

// ---------------------------------------------------------------------------
// Batched fp32 -> bf16 conversion of x, in_proj_w, dt_proj_w, out_proj_w.
// Segment boundaries are multiples of 4.
// ---------------------------------------------------------------------------
#define S_X   (NROW * D_MODEL)                 // 4,194,304
#define S_IN  (2 * D_INNER * D_MODEL)          // 4,194,304
#define S_DT  (D_INNER * DT_RANK)              //   131,072
#define S_OUT (D_MODEL * D_INNER)              // 2,097,152
#define S_TOT (S_X + S_IN + S_DT + S_OUT)      // 10,616,832

__global__ __launch_bounds__(256) void cvt_all(
    const float* __restrict__ x,   const float* __restrict__ inw,
    const float* __restrict__ dtw, const float* __restrict__ outw,
    unsigned short* __restrict__ x_bf,   unsigned short* __restrict__ inw_bf,
    unsigned short* __restrict__ dtw_bf, unsigned short* __restrict__ outw_bf)
{
    const int i = (blockIdx.x * 256 + threadIdx.x) * 4;
    if (i >= S_TOT) return;
    const float* src; unsigned short* dst; int off;
    if (i < S_X)                { src = x;    dst = x_bf;    off = i; }
    else if (i < S_X + S_IN)    { src = inw;  dst = inw_bf;  off = i - S_X; }
    else if (i < S_X + S_IN + S_DT) { src = dtw; dst = dtw_bf; off = i - S_X - S_IN; }
    else                        { src = outw; dst = outw_bf; off = i - S_X - S_IN - S_DT; }
    const float4 v = *(const float4*)(src + off);
    ushort4 o;
    o.x = f2bf(v.x); o.y = f2bf(v.y); o.z = f2bf(v.z); o.w = f2bf(v.w);
    *(ushort4*)(dst + off) = o;
}

// x_proj_w [96][2048] -> bf16 padded to [128][2048] (rows 96..127 zero)
__global__ __launch_bounds__(256) void cvt_pad_xpw(
    const float* __restrict__ src, unsigned short* __restrict__ dst)
{
    const int i = (blockIdx.x * 256 + threadIdx.x) * 4;   // < 128*2048
    const int row = i >> 11;
    ushort4 o = make_ushort4(0, 0, 0, 0);
    if (row < 96) {
        const float4 v = *(const float4*)(src + (size_t)row * 2048 + (i & 2047));
        o.x = f2bf(v.x); o.y = f2bf(v.y); o.z = f2bf(v.z); o.w = f2bf(v.w);
    }
    *(ushort4*)(dst + i) = o;
}

// ---------------------------------------------------------------------------
// bf16 MFMA GEMM:  C[M,N] = A[M,K](bf16) @ B[N,K](bf16)^T, fp32 accumulate.
// 128x128 tile, BK=64, 4 waves, 4x4 frags of 16x16x32.
// mode 0: fp32 C  |  mode 1: fp32 softplus(c+bias[col])  |  mode 2: bf16 C
// mode 2 uses an LDS-transposed epilogue for coalesced 16B stores.
// ---------------------------------------------------------------------------
__global__ __launch_bounds__(256) void gemm_bf16(
    const unsigned short* __restrict__ A, int lda,
    const unsigned short* __restrict__ B, int ldb,
    float* __restrict__ C, unsigned short* __restrict__ Cb, int ldc,
    int K, const float* __restrict__ bias, int mode)
{
    __shared__ unsigned short As[8][128 * 8];   // 16 KB
    __shared__ unsigned short Bs[8][128 * 8];   // 16 KB

    const int tid  = threadIdx.x;
    const int lane = tid & 63;
    const int w    = tid >> 6;
    const int wr   = w >> 1;
    const int wc   = w & 1;
    const int q    = lane >> 4;
    const int m    = lane & 15;
    const int row0 = blockIdx.y * 128;
    const int col0 = blockIdx.x * 128;

    f32x4 acc[4][4];
#pragma unroll
    for (int i = 0; i < 4; i++)
#pragma unroll
        for (int j = 0; j < 4; j++) acc[i][j] = (f32x4){0.f, 0.f, 0.f, 0.f};

    for (int k0 = 0; k0 < K; k0 += 64) {
#pragma unroll
        for (int i = 0; i < 4; i++) {
            const int c    = w * 4 + i;
            const int kb   = c >> 1;
            const int half = c & 1;
            const unsigned short* ga =
                A + (size_t)(row0 + half * 64 + lane) * lda + k0 + kb * 8;
            const unsigned short* gb =
                B + (size_t)(col0 + half * 64 + lane) * ldb + k0 + kb * 8;
            __builtin_amdgcn_global_load_lds(
                (const __attribute__((address_space(1))) unsigned int*)ga,
                (__attribute__((address_space(3))) unsigned int*)&As[kb][half * 512],
                16, 0, 0);
            __builtin_amdgcn_global_load_lds(
                (const __attribute__((address_space(1))) unsigned int*)gb,
                (__attribute__((address_space(3))) unsigned int*)&Bs[kb][half * 512],
                16, 0, 0);
        }
        __syncthreads();

#pragma unroll
        for (int dep = 0; dep < 2; dep++) {
            bf16x8 af[4], bfr[4];
#pragma unroll
            for (int t = 0; t < 4; t++) {
                af[t]  = *(const bf16x8*)&As[dep * 4 + q][(wr * 64 + t * 16 + m) * 8];
                bfr[t] = *(const bf16x8*)&Bs[dep * 4 + q][(wc * 64 + t * 16 + m) * 8];
            }
#pragma unroll
            for (int mt = 0; mt < 4; mt++)
#pragma unroll
                for (int nt = 0; nt < 4; nt++)
                    acc[mt][nt] = __builtin_amdgcn_mfma_f32_16x16x32_bf16(
                        af[mt], bfr[nt], acc[mt][nt], 0, 0, 0);
        }
        __syncthreads();
    }

    if (mode == 2) {
        // bf16 epilogue through LDS: two 64-row halves, reuse As (8192 shorts)
        unsigned short* ep = &As[0][0];
#pragma unroll
        for (int hh = 0; hh < 2; hh++) {
            if (wr == hh) {
#pragma unroll
                for (int mt = 0; mt < 4; mt++)
#pragma unroll
                    for (int nt = 0; nt < 4; nt++)
#pragma unroll
                        for (int r = 0; r < 4; r++)
                            ep[(mt * 16 + q * 4 + r) * 128 + wc * 64 + nt * 16 + m] =
                                f2bf(acc[mt][nt][r]);
            }
            __syncthreads();
#pragma unroll
            for (int i = 0; i < 4; i++) {
                const int c    = i * 256 + tid;       // 0..1023
                const int rrow = c >> 4;
                const int off  = (c & 15) * 8;
                *(ushort8*)(Cb + (size_t)(row0 + hh * 64 + rrow) * ldc + col0 + off) =
                    *(const ushort8*)&ep[rrow * 128 + off];
            }
            __syncthreads();
        }
        return;
    }

#pragma unroll
    for (int mt = 0; mt < 4; mt++) {
#pragma unroll
        for (int nt = 0; nt < 4; nt++) {
            const int col = col0 + wc * 64 + nt * 16 + m;
            float bcol = 0.f;
            if (mode == 1) bcol = bias[col];
#pragma unroll
            for (int r = 0; r < 4; r++) {
                const int row = row0 + wr * 64 + mt * 16 + q * 4 + r;
                float v = acc[mt][nt][r];
                if (mode == 1) v = softplus_f(v + bcol);
                C[(size_t)row * ldc + col] = v;
            }
        }
    }
}

// ---------------------------------------------------------------------------
// GEMM3 bf16 split-K: x_dbl = xc_bf[4096,2048] @ xpw_pad[128,2048]^T.
// ---------------------------------------------------------------------------
#define G3Z 8

__global__ __launch_bounds__(256) void gemm3_bf16_splitk(
    const unsigned short* __restrict__ A,   // [4096][2048]
    const unsigned short* __restrict__ B,   // [128][2048] padded
    float* __restrict__ Cp)                 // [G3Z][4096][96]
{
    __shared__ unsigned short As[8][128 * 8];
    __shared__ unsigned short Bs[8][128 * 8];

    const int tid  = threadIdx.x;
    const int lane = tid & 63;
    const int w    = tid >> 6;
    const int wr   = w >> 1;
    const int wc   = w & 1;
    const int q    = lane >> 4;
    const int m    = lane & 15;
    const int row0 = blockIdx.y * 128;
    const int kz0  = blockIdx.z * (2048 / G3Z);

    f32x4 acc[4][4];
#pragma unroll
    for (int i = 0; i < 4; i++)
#pragma unroll
        for (int j = 0; j < 4; j++) acc[i][j] = (f32x4){0.f, 0.f, 0.f, 0.f};

    for (int k0 = kz0; k0 < kz0 + (2048 / G3Z); k0 += 64) {
#pragma unroll
        for (int i = 0; i < 4; i++) {
            const int c    = w * 4 + i;
            const int kb   = c >> 1;
            const int half = c & 1;
            const unsigned short* ga =
                A + (size_t)(row0 + half * 64 + lane) * 2048 + k0 + kb * 8;
            const unsigned short* gb =
                B + (size_t)(half * 64 + lane) * 2048 + k0 + kb * 8;
            __builtin_amdgcn_global_load_lds(
                (const __attribute__((address_space(1))) unsigned int*)ga,
                (__attribute__((address_space(3))) unsigned int*)&As[kb][half * 512],
                16, 0, 0);
            __builtin_amdgcn_global_load_lds(
                (const __attribute__((address_space(1))) unsigned int*)gb,
                (__attribute__((address_space(3))) unsigned int*)&Bs[kb][half * 512],
                16, 0, 0);
        }
        __syncthreads();

#pragma unroll
        for (int dep = 0; dep < 2; dep++) {
            bf16x8 af[4], bfr[4];
#pragma unroll
            for (int t = 0; t < 4; t++) {
                af[t]  = *(const bf16x8*)&As[dep * 4 + q][(wr * 64 + t * 16 + m) * 8];
                bfr[t] = *(const bf16x8*)&Bs[dep * 4 + q][(wc * 64 + t * 16 + m) * 8];
            }
#pragma unroll
            for (int mt = 0; mt < 4; mt++)
#pragma unroll
                for (int nt = 0; nt < 4; nt++)
                    acc[mt][nt] = __builtin_amdgcn_mfma_f32_16x16x32_bf16(
                        af[mt], bfr[nt], acc[mt][nt], 0, 0, 0);
        }
        __syncthreads();
    }

    float* Cz = Cp + (size_t)blockIdx.z * NROW * 96;
#pragma unroll
    for (int mt = 0; mt < 4; mt++) {
#pragma unroll
        for (int nt = 0; nt < 4; nt++) {
            const int col = wc * 64 + nt * 16 + m;
            if (col < 96) {
#pragma unroll
                for (int r = 0; r < 4; r++) {
                    const int row = row0 + wr * 64 + mt * 16 + q * 4 + r;
                    Cz[(size_t)row * 96 + col] = acc[mt][nt][r];
                }
            }
        }
    }
}

__global__ __launch_bounds__(256) void reduce3(
    const float* __restrict__ Cp,
    float* __restrict__ xdbl,
    unsigned short* __restrict__ xdbl_bf)
{
    const int idx = blockIdx.x * 256 + threadIdx.x;   // < 4096*96
    float s = 0.f;
#pragma unroll
    for (int z = 0; z < G3Z; z++)
        s += Cp[(size_t)z * NROW * 96 + idx];
    xdbl[idx] = s;
    xdbl_bf[idx] = f2bf(s);
}

// ---------------------------------------------------------------------------
// Causal depthwise conv1d (K=4, left-pad 3) + bias + SiLU. bf16 in/out.
// ---------------------------------------------------------------------------
__global__ __launch_bounds__(256) void conv_silu_kernel(
    const unsigned short* __restrict__ xz,   // [NROW][2*D_INNER] bf16
    const float* __restrict__ conv_w,
    const float* __restrict__ conv_b,
    unsigned short* __restrict__ xc_bf)      // [NROW][D_INNER] bf16
{
    const int idx = blockIdx.x * 256 + threadIdx.x;   // over NROW*D_INNER
    const int d  = idx & (D_INNER - 1);
    const int rt = idx >> 11;
    const int t  = rt & (L_SEQ - 1);

    const float w0 = conv_w[d * 4 + 0];
    const float w1 = conv_w[d * 4 + 1];
    const float w2 = conv_w[d * 4 + 2];
    const float w3 = conv_w[d * 4 + 3];

    const unsigned short* col = xz + d;
    float acc = conv_b[d];
    if (t >= 3) acc = fmaf(w0, bf2f(col[(size_t)(rt - 3) * (2 * D_INNER)]), acc);
    if (t >= 2) acc = fmaf(w1, bf2f(col[(size_t)(rt - 2) * (2 * D_INNER)]), acc);
    if (t >= 1) acc = fmaf(w2, bf2f(col[(size_t)(rt - 1) * (2 * D_INNER)]), acc);
    acc = fmaf(w3, bf2f(col[(size_t)rt * (2 * D_INNER)]), acc);
    const float sig = 1.f / (1.f + __expf(-acc));
    xc_bf[idx] = f2bf(acc * sig);
}

// ---------------------------------------------------------------------------
// Chunked parallel selective scan, thread-per-d with h[16] in registers.
// ---------------------------------------------------------------------------
#define G_CHUNK 32
#define T_CHUNK (L_SEQ / G_CHUNK)   // 64

__global__ __launch_bounds__(256) void scan_pass1(
    const float* __restrict__ dtbuf,            // [NROW][D_INNER] fp32
    const unsigned short* __restrict__ xc,      // [NROW][D_INNER] bf16
    const float* __restrict__ xdbl,             // [NROW][96]
    const float* __restrict__ A_log,            // [D_INNER][16]
    float* __restrict__ aprod,                  // [G][B][16][D_INNER]
    float* __restrict__ hend)
{
    __shared__ float B_s[T_CHUNK][16];

    const int tid = threadIdx.x;
    const int g   = blockIdx.x;
    const int db  = blockIdx.y;
    const int b   = db >> 3;
    const int d   = (db & 7) * 256 + tid;
    const size_t rowbase = (size_t)b * L_SEQ + (size_t)g * T_CHUNK;

    {
        const int tt = tid >> 2, q4 = (tid & 3) * 4;
        *(float4*)&B_s[tt][q4] =
            *(const float4*)&xdbl[(rowbase + tt) * 96 + DT_RANK + q4];
    }

    float A_dn[16];
#pragma unroll
    for (int n = 0; n < 16; n++)
        A_dn[n] = -expf(A_log[(size_t)d * D_STATE + n]);

    float h[16], ap[16];
#pragma unroll
    for (int n = 0; n < 16; n++) { h[n] = 0.f; ap[n] = 1.f; }

    __syncthreads();

#pragma unroll 2
    for (int t = 0; t < T_CHUNK; t++) {
        const size_t r = rowbase + t;
        const float dtv = dtbuf[r * D_INNER + d];
        const float xv  = bf2f(xc[r * D_INNER + d]);
        const float dtx = dtv * xv;
        float Bv[16];
        *(float4*)&Bv[0]  = *(const float4*)&B_s[t][0];
        *(float4*)&Bv[4]  = *(const float4*)&B_s[t][4];
        *(float4*)&Bv[8]  = *(const float4*)&B_s[t][8];
        *(float4*)&Bv[12] = *(const float4*)&B_s[t][12];
#pragma unroll
        for (int n = 0; n < 16; n++) {
            const float dA = __expf(dtv * A_dn[n]);
            ap[n] *= dA;
            h[n] = fmaf(dA, h[n], dtx * Bv[n]);
        }
    }

    const size_t base = ((size_t)g * B_SZ + b) * D_STATE * D_INNER + d;
#pragma unroll
    for (int n = 0; n < 16; n++) {
        aprod[base + (size_t)n * D_INNER] = ap[n];
        hend[base + (size_t)n * D_INNER]  = h[n];
    }
}

__global__ __launch_bounds__(256) void scan_pass2(
    const float* __restrict__ aprod,
    const float* __restrict__ hend,
    float* __restrict__ H0)
{
    const int idx = blockIdx.x * 256 + threadIdx.x;
    const size_t stride = (size_t)B_SZ * D_STATE * D_INNER;
    float h = 0.f;
#pragma unroll
    for (int g = 0; g < G_CHUNK; g++) {
        H0[(size_t)g * stride + idx] = h;
        h = fmaf(aprod[(size_t)g * stride + idx], h, hend[(size_t)g * stride + idx]);
    }
}

__global__ __launch_bounds__(256) void scan_pass3(
    const float* __restrict__ dtbuf,
    const unsigned short* __restrict__ xc,     // bf16
    const unsigned short* __restrict__ xz,     // bf16, z at +D_INNER
    const float* __restrict__ xdbl,
    const float* __restrict__ A_log,
    const float* __restrict__ Dvec,
    const float* __restrict__ H0,
    unsigned short* __restrict__ y)            // bf16
{
    __shared__ float B_s[T_CHUNK][16];
    __shared__ float C_s[T_CHUNK][16];

    const int tid = threadIdx.x;
    const int g   = blockIdx.x;
    const int db  = blockIdx.y;
    const int b   = db >> 3;
    const int d   = (db & 7) * 256 + tid;
    const size_t rowbase = (size_t)b * L_SEQ + (size_t)g * T_CHUNK;

    {
        const int tt = tid >> 2, q4 = (tid & 3) * 4;
        *(float4*)&B_s[tt][q4] =
            *(const float4*)&xdbl[(rowbase + tt) * 96 + DT_RANK + q4];
        *(float4*)&C_s[tt][q4] =
            *(const float4*)&xdbl[(rowbase + tt) * 96 + DT_RANK + D_STATE + q4];
    }

    float A_dn[16];
#pragma unroll
    for (int n = 0; n < 16; n++)
        A_dn[n] = -expf(A_log[(size_t)d * D_STATE + n]);
    const float D_d = Dvec[d];

    float h[16];
    const size_t base = ((size_t)g * B_SZ + b) * D_STATE * D_INNER + d;
#pragma unroll
    for (int n = 0; n < 16; n++)
        h[n] = H0[base + (size_t)n * D_INNER];

    __syncthreads();

#pragma unroll 2
    for (int t = 0; t < T_CHUNK; t++) {
        const size_t r = rowbase + t;
        const float dtv = dtbuf[r * D_INNER + d];
        const float xv  = bf2f(xc[r * D_INNER + d]);
        const float zv  = bf2f(xz[r * (2 * D_INNER) + D_INNER + d]);
        const float dtx = dtv * xv;
        float Bv[16], Cv[16];
        *(float4*)&Bv[0]  = *(const float4*)&B_s[t][0];
        *(float4*)&Bv[4]  = *(const float4*)&B_s[t][4];
        *(float4*)&Bv[8]  = *(const float4*)&B_s[t][8];
        *(float4*)&Bv[12] = *(const float4*)&B_s[t][12];
        *(float4*)&Cv[0]  = *(const float4*)&C_s[t][0];
        *(float4*)&Cv[4]  = *(const float4*)&C_s[t][4];
        *(float4*)&Cv[8]  = *(const float4*)&C_s[t][8];
        *(float4*)&Cv[12] = *(const float4*)&C_s[t][12];
        float dot = 0.f;
#pragma unroll
        for (int n = 0; n < 16; n++) {
            const float dA = __expf(dtv * A_dn[n]);
            h[n] = fmaf(dA, h[n], dtx * Bv[n]);
            dot = fmaf(h[n], Cv[n], dot);
        }
        const float sig = 1.f / (1.f + __expf(-zv));
        const float yv = (dot + D_d * xv) * (zv * sig);
        y[r * D_INNER + d] = f2bf(yv);
    }
}

// ---------------------------------------------------------------------------
extern "C" void kernel_launch(void* const* d_in, const int* in_sizes, int n_in,
                              void* d_out, int out_size, void* d_ws, size_t ws_size,
                              hipStream_t stream) {
    const float* x          = (const float*)d_in[0];
    const float* in_proj_w  = (const float*)d_in[1];
    const float* conv_w     = (const float*)d_in[2];
    const float* conv_b     = (const float*)d_in[3];
    const float* x_proj_w   = (const float*)d_in[4];
    const float* dt_proj_w  = (const float*)d_in[5];
    const float* dt_proj_b  = (const float*)d_in[6];
    const float* A_log      = (const float*)d_in[7];
    const float* Dv         = (const float*)d_in[8];
    const float* out_proj_w = (const float*)d_in[9];
    float* out = (float*)d_out;

    float* ws = (float*)d_ws;
    float* xdbl = ws;                                   //   393,216 f
    float* dtb  = xdbl + (size_t)393216;                // 8,388,608 f
    float* apr  = dtb  + (size_t)8388608;               // 2,097,152 f
    float* hen  = apr  + (size_t)2097152;               // 2,097,152 f
    float* H0   = hen  + (size_t)2097152;               // 2,097,152 f
    float* Cp   = H0   + (size_t)2097152;               // 3,145,728 f
    unsigned short* xz_bf   = (unsigned short*)(Cp + 3145728);  // 16,777,216 us
    unsigned short* xc_bf   = xz_bf   + (size_t)16777216;       //  8,388,608 us
    unsigned short* yb_bf   = xc_bf   + (size_t)8388608;        //  8,388,608 us
    unsigned short* x_bf    = yb_bf   + (size_t)8388608;        //  4,194,304 us
    unsigned short* inw_bf  = x_bf    + (size_t)4194304;        //  4,194,304 us
    unsigned short* dtw_bf  = inw_bf  + (size_t)4194304;        //    131,072 us
    unsigned short* outw_bf = dtw_bf  + (size_t)131072;         //  2,097,152 us
    unsigned short* xpw_bf  = outw_bf + (size_t)2097152;        //    262,144 us
    unsigned short* xdbl_bf = xpw_bf  + (size_t)262144;         //    393,216 us

    dim3 blk(256);

    // 0) conversions (2 launches)
    cvt_all<<<dim3((S_TOT / 4 + 255) / 256), blk, 0, stream>>>(
        x, in_proj_w, dt_proj_w, out_proj_w, x_bf, inw_bf, dtw_bf, outw_bf);
    cvt_pad_xpw<<<dim3(256), blk, 0, stream>>>(x_proj_w, xpw_bf);

    // 1) xz = x @ in_proj_w^T   (M=4096, N=4096, K=1024) -> bf16
    gemm_bf16<<<dim3(32, 32), blk, 0, stream>>>(
        x_bf, D_MODEL, inw_bf, D_MODEL, nullptr, xz_bf, 2 * D_INNER,
        D_MODEL, nullptr, 2);

    // 2) conv + bias + SiLU -> xc_bf
    conv_silu_kernel<<<dim3((NROW * D_INNER) / 256), blk, 0, stream>>>(
        xz_bf, conv_w, conv_b, xc_bf);

    // 3) x_dbl = xc @ x_proj_w^T (split-K bf16)
    gemm3_bf16_splitk<<<dim3(1, 32, G3Z), blk, 0, stream>>>(xc_bf, xpw_bf, Cp);
    reduce3<<<dim3((NROW * 96) / 256), blk, 0, stream>>>(Cp, xdbl, xdbl_bf);

    // 4) dt = softplus(dt_r @ dt_proj_w^T + b)  (M=4096, N=2048, K=64) -> fp32
    gemm_bf16<<<dim3(16, 32), blk, 0, stream>>>(
        xdbl_bf, 96, dtw_bf, DT_RANK, dtb, nullptr, D_INNER,
        DT_RANK, dt_proj_b, 1);

    // 5) chunked parallel selective scan -> yb (bf16)
    scan_pass1<<<dim3(G_CHUNK, 16), blk, 0, stream>>>(
        dtb, xc_bf, xdbl, A_log, apr, hen);
    scan_pass2<<<dim3(B_SZ * D_STATE * D_INNER / 256), blk, 0, stream>>>(
        apr, hen, H0);
    scan_pass3<<<dim3(G_CHUNK, 16), blk, 0, stream>>>(
        dtb, xc_bf, xz_bf, xdbl, A_log, Dv, H0, yb_bf);

    // 6) out = y @ out_proj_w^T  (M=4096, N=1024, K=2048) -> fp32
    gemm_bf16<<<dim3(8, 32), blk, 0, stream>>>(
        yb_bf, D_INNER, outw_bf, D_INNER, out, nullptr, D_MODEL,
        D_INNER, nullptr, 0);
}